// Round 1
// baseline (193.762 us; speedup 1.0000x reference)
//
#include <hip/hip_runtime.h>
#include <stdint.h>

typedef float  v4f  __attribute__((ext_vector_type(4)));
typedef int    v4i  __attribute__((ext_vector_type(4)));
typedef __bf16 v8bf __attribute__((ext_vector_type(8)));
typedef __bf16 v4bf __attribute__((ext_vector_type(4)));

#define BATCH  2
#define NQ     4096
#define MK     1024
#define DMODEL 512
#define DCTX   768
#define NH     8
#define DH     64

// Weights-only prep: 1536 blocks transpose weights to Wt[512][K] bf16.
// Block 0 zero-inits scal. (x/ctx bf16 staging removed: the QKV GEMM now
// converts fp32->bf16 inline with the identical RNE cast -> bits unchanged.)
__global__ __launch_bounds__(256) void k_prep(
    const float* __restrict__ Wq, const float* __restrict__ Wk,
    const float* __restrict__ Wv, const float* __restrict__ Wo,
    __bf16* __restrict__ Wq_t, __bf16* __restrict__ Wk_t,
    __bf16* __restrict__ Wv_t, __bf16* __restrict__ Wo_t,
    unsigned* __restrict__ scal) {
  int id = blockIdx.x;
  if (id == 0 && threadIdx.x < 4) scal[threadIdx.x] = 0u;
  int tx = id & 15, rem = id >> 4;
  int ty = rem % 24, tz = rem / 24;
  const float* src; __bf16* dst; int K;
  switch (tz) {
    case 0:  src = Wq; dst = Wq_t; K = DMODEL; break;
    case 1:  src = Wk; dst = Wk_t; K = DCTX;   break;
    case 2:  src = Wv; dst = Wv_t; K = DCTX;   break;
    default: src = Wo; dst = Wo_t; K = DMODEL; break;
  }
  int k0 = ty * 32;
  if (k0 >= K) return;
  int n0 = tx * 32;
  __shared__ __bf16 tile[32][33];
  int c = threadIdx.x & 31, r0 = threadIdx.x >> 5;
  for (int i = 0; i < 4; ++i) {
    int r = r0 + i * 8;
    tile[c][r] = (__bf16)src[(size_t)(k0 + r) * DMODEL + n0 + c];
  }
  __syncthreads();
  for (int i = 0; i < 4; ++i) {
    int r = r0 + i * 8;
    dst[(size_t)(n0 + r) * K + k0 + c] = tile[r][c];
  }
}

// A-fragment loaders: bf16 direct, or fp32 with inline RNE cvt (bit-identical
// to the old prep staging path).
__device__ __forceinline__ v8bf load_a8(const __bf16* p) {
  return *(const v8bf*)p;
}
__device__ __forceinline__ v8bf load_a8(const float* p) {
  float4 a = *(const float4*)p, b = *(const float4*)(p + 4);
  v8bf o = { (__bf16)a.x, (__bf16)a.y, (__bf16)a.z, (__bf16)a.w,
             (__bf16)b.x, (__bf16)b.y, (__bf16)b.z, (__bf16)b.w };
  return o;
}

// B-stationary GEMM body: C[.][N] tile = A[128 rows][K_] @ Bt[NC cols][K_]^T.
// NC-col B panel for ALL K in LDS (one barrier); K-loop barrier-free.
// Per-element k-ascending MFMA chain identical for any NC -> bit-identical C.
template<int K_, int NC, bool BIAS, bool AMAX, typename AT>
__device__ __forceinline__ void gemm_body(
    char* smemraw, const AT* __restrict__ A, const __bf16* __restrict__ Bt,
    float* __restrict__ C, int N, int rowBlk, int colBlk,
    const float* __restrict__ bias,
    unsigned* __restrict__ amaxLo, unsigned* __restrict__ amaxHi) {
  constexpr int CS = K_ + 8;
  constexpr int GPC = K_ / 8;
  constexpr int JT = NC / 16;
  __bf16* Bs = (__bf16*)smemraw;
  float* redmax = (float*)(smemraw + (size_t)NC * CS * 2);
  const int tid = threadIdx.x;
  const int lane = tid & 63, wave = tid >> 6;
  const int l15 = lane & 15, g = lane >> 4;
  const int col0 = colBlk * NC;
  const int row0w = rowBlk * 128 + wave * 32;

#pragma unroll
  for (int i = 0; i < NC * GPC / 256; ++i) {
    int f = i * 256 + tid;
    int c = f / GPC, w = f - c * GPC;
    *(v8bf*)(&Bs[c * CS + w * 8]) =
        *(const v8bf*)(Bt + (size_t)(col0 + c) * K_ + w * 8);
  }
  __syncthreads();

  v4f acc[2][JT] = {};
  const AT* a0 = A + (size_t)(row0w + l15) * K_ + g * 8;
  const AT* a1 = A + (size_t)(row0w + 16 + l15) * K_ + g * 8;
#pragma unroll
  for (int k0 = 0; k0 < K_; k0 += 32) {
    v8bf af0 = load_a8(a0 + k0);
    v8bf af1 = load_a8(a1 + k0);
#pragma unroll
    for (int j = 0; j < JT; ++j) {
      v8bf bfj = *(const v8bf*)(&Bs[(j * 16 + l15) * CS + k0 + g * 8]);
      acc[0][j] = __builtin_amdgcn_mfma_f32_16x16x32_bf16(af0, bfj, acc[0][j], 0, 0, 0);
      acc[1][j] = __builtin_amdgcn_mfma_f32_16x16x32_bf16(af1, bfj, acc[1][j], 0, 0, 0);
    }
  }

  float lmax = 0.0f;
#pragma unroll
  for (int j = 0; j < JT; ++j) {
    int col = col0 + j * 16 + l15;
    float bv = BIAS ? bias[col] : 0.0f;
#pragma unroll
    for (int i = 0; i < 2; ++i) {
#pragma unroll
      for (int r = 0; r < 4; ++r) {
        int row = row0w + i * 16 + g * 4 + r;  // C/D: col=lane&15, row=quad*4+reg
        float cv = acc[i][j][r] + bv;
        C[(size_t)row * N + col] = cv;
        if (AMAX) lmax = fmaxf(lmax, fabsf(cv));
      }
    }
  }
  if (AMAX) {
    for (int off = 32; off > 0; off >>= 1)
      lmax = fmaxf(lmax, __shfl_xor(lmax, off, 64));
    if (lane == 0) redmax[wave] = lmax;
    __syncthreads();
    if (tid == 0) {
      float bm = fmaxf(fmaxf(redmax[0], redmax[1]), fmaxf(redmax[2], redmax[3]));
      atomicMax(col0 < 512 ? amaxLo : amaxHi, __float_as_uint(bm));
    }
  }
}

// Fused projections: blocks [0,512) = q GEMM (8192x512, K=512, 64-col panels);
// [512,1024) = kv GEMM (2048x1024, K=768, 32-col panels). A is read directly
// from fp32 x/ctx with inline bf16 cvt. Column panel is the fastest block
// index so consecutive blocks share the A row-panel (L2 reuse).
__global__ __launch_bounds__(256, 2) void k_gemm_qkv(
    const float* __restrict__ x, const __bf16* __restrict__ Wq_t,
    float* __restrict__ qf,
    const float* __restrict__ ctx, const __bf16* __restrict__ Wkv_t,
    float* __restrict__ kvf, unsigned* __restrict__ scal) {
  __shared__ __align__(16) char smem[64 * (512 + 8) * 2 + 16];
  int bid = blockIdx.x;
  if (bid < 512) {
    gemm_body<512, 64, false, true, float>(smem, x, Wq_t, qf, 512,
                                           bid >> 3, bid & 7, nullptr,
                                           scal + 0, scal + 0);
  } else {
    int id = bid - 512;
    gemm_body<768, 32, false, true, float>(smem, ctx, Wkv_t, kvf, 1024,
                                           id >> 5, id & 31, nullptr,
                                           scal + 1, scal + 2);
  }
}

__global__ __launch_bounds__(256, 2) void k_gemm_out(
    const __bf16* __restrict__ o, const __bf16* __restrict__ Wo_t,
    float* __restrict__ out, const float* __restrict__ bo) {
  __shared__ __align__(16) char smem[64 * (512 + 8) * 2 + 16];
  gemm_body<512, 64, true, false, __bf16>(smem, o, Wo_t, out, 512,
                                          blockIdx.x >> 3, blockIdx.x & 7, bo,
                                          nullptr, nullptr);
}

// k/v quantization: blocks [0,1024) quantize k; [1024,1280) transpose-quantize v.
__global__ __launch_bounds__(256) void k_quant_kv(
    const float* __restrict__ kvf,
    int8_t* __restrict__ k8, int8_t* __restrict__ v8t,
    const unsigned* __restrict__ scal) {
  __shared__ int8_t tile[64][80];
  int bx = blockIdx.x;
  if (bx < 1024) {
    int j = bx * 256 + threadIdx.x;
    int r = j >> 7;
    int c4 = (j & 127) << 2;
    float4 v = *(const float4*)(kvf + (size_t)r * 1024 + c4);
    float s = 127.0f / __uint_as_float(scal[1]);
    int a0 = __float2int_rn(v.x * s), a1 = __float2int_rn(v.y * s);
    int a2 = __float2int_rn(v.z * s), a3 = __float2int_rn(v.w * s);
    a0 = max(-128, min(127, a0)); a1 = max(-128, min(127, a1));
    a2 = max(-128, min(127, a2)); a3 = max(-128, min(127, a3));
    unsigned p = (unsigned)(a0 & 255) | ((unsigned)(a1 & 255) << 8) |
                 ((unsigned)(a2 & 255) << 16) | ((unsigned)(a3 & 255) << 24);
    *(unsigned*)(k8 + (size_t)j * 4) = p;
    return;
  }
  int id = bx - 1024;
  int bh = id >> 4, b = bh >> 3, h = bh & 7;
  int j0 = (id & 15) * 64;
  const float s = 127.0f / __uint_as_float(scal[2]);
  int t = threadIdx.x;
  int j = t >> 2, dh0 = (t & 3) << 4;
  const float* src = kvf + (size_t)(b * MK + j0 + j) * 1024 + 512 + h * DH + dh0;
#pragma unroll
  for (int i = 0; i < 16; i += 4) {
    float4 v = *(const float4*)(src + i);
    int a0 = __float2int_rn(v.x * s), a1 = __float2int_rn(v.y * s);
    int a2 = __float2int_rn(v.z * s), a3 = __float2int_rn(v.w * s);
    tile[dh0 + i + 0][j] = (int8_t)max(-128, min(127, a0));
    tile[dh0 + i + 1][j] = (int8_t)max(-128, min(127, a1));
    tile[dh0 + i + 2][j] = (int8_t)max(-128, min(127, a2));
    tile[dh0 + i + 3][j] = (int8_t)max(-128, min(127, a3));
  }
  __syncthreads();
  int dh = t >> 2, jb = (t & 3) << 4;
  v4i val = *(const v4i*)(&tile[dh][jb]);
  *(v4i*)(v8t + (size_t)(bh * DH + dh) * MK + j0 + jb) = val;
}

__device__ __forceinline__ v4i quant_pack16(const float* p, float s) {
  v4i out;
#pragma unroll
  for (int q = 0; q < 4; ++q) {
    float4 v = *(const float4*)(p + q * 4);
    int a0 = __float2int_rn(v.x * s), a1 = __float2int_rn(v.y * s);
    int a2 = __float2int_rn(v.z * s), a3 = __float2int_rn(v.w * s);
    a0 = max(-128, min(127, a0)); a1 = max(-128, min(127, a1));
    a2 = max(-128, min(127, a2)); a3 = max(-128, min(127, a3));
    out[q] = (int)((unsigned)(a0 & 255) | ((unsigned)(a1 & 255) << 8) |
                   ((unsigned)(a2 & 255) << 16) | ((unsigned)(a3 & 255) << 24));
  }
  return out;
}

// pass 1: waves split q-rows (16 each); 8 tiles of 128 keys staged in LDS.
// T14 prefetch: next tile's K loaded into registers during compute, ds_write
// after the barrier -> HBM/L2 latency hidden. z summation tree unchanged ->
// bit-identical invz.
__global__ __launch_bounds__(256, 4) void k_pass1(
    const float* __restrict__ qf, int8_t* __restrict__ q8,
    const int8_t* __restrict__ k8,
    float* __restrict__ invz, unsigned* __restrict__ scal) {
  __shared__ __align__(16) int8_t kbuf[128 * 72];
  __shared__ float mared[4];
  int bh = blockIdx.y, b = bh >> 3, h = bh & 7;
  int wave = threadIdx.x >> 6, lane = threadIdx.x & 63;
  int l15 = lane & 15, g = lane >> 4;
  int row0 = blockIdx.x * 64;
  int myrow = row0 + wave * 16 + l15;
  const float aq = __uint_as_float(scal[0]), ak = __uint_as_float(scal[1]);
  const float alpha2 = (aq * ak) * (0.125f / (127.0f * 127.0f)) * 1.44269504f;
  const float sq = 127.0f / aq;
  const v4i z4 = {0, 0, 0, 0};
  size_t qoff = (size_t)(b * NQ + myrow) * DMODEL + h * DH + g * 16;
  v4i qfrag = quant_pack16(qf + qoff, sq);
  *(v4i*)(q8 + qoff) = qfrag;
  const int8_t* kbase = k8 + (size_t)b * MK * DMODEL + h * DH;
  const int rs = threadIdx.x >> 2, qs = (threadIdx.x & 3) * 16;
  const int8_t* kls = kbase + (size_t)rs * DMODEL + qs;

  v4i kp0 = *(const v4i*)(kls);
  v4i kp1 = *(const v4i*)(kls + (size_t)64 * DMODEL);

  float z[4] = {0.f, 0.f, 0.f, 0.f};
  int mi = -(1 << 30);
  for (int tile = 0; tile < 8; ++tile) {
    __syncthreads();
    *(v4i*)(&kbuf[rs * 72 + qs]) = kp0;
    *(v4i*)(&kbuf[(rs + 64) * 72 + qs]) = kp1;
    __syncthreads();
    if (tile < 7) {  // prefetch next tile; latency hides under compute below
      kp0 = *(const v4i*)(kls + (size_t)((tile + 1) * 128) * DMODEL);
      kp1 = *(const v4i*)(kls + (size_t)((tile + 1) * 128 + 64) * DMODEL);
    }
    float zt = z[tile >> 1];
#pragma unroll
    for (int t = 0; t < 8; ++t) {
      v4i kfrag = *(const v4i*)(&kbuf[(t * 16 + l15) * 72 + g * 16]);
      v4i sa = __builtin_amdgcn_mfma_i32_16x16x64_i8(kfrag, qfrag, z4, 0, 0, 0);
      mi = max(mi, max(max(sa[0], sa[1]), max(sa[2], sa[3])));
      float e0 = __builtin_amdgcn_exp2f((float)sa[0] * alpha2);
      float e1 = __builtin_amdgcn_exp2f((float)sa[1] * alpha2);
      float e2 = __builtin_amdgcn_exp2f((float)sa[2] * alpha2);
      float e3 = __builtin_amdgcn_exp2f((float)sa[3] * alpha2);
      zt += (e0 + e1) + (e2 + e3);
    }
    z[tile >> 1] = zt;
  }
#pragma unroll
  for (int i = 0; i < 4; ++i) {
    z[i] += __shfl_xor(z[i], 16, 64);
    z[i] += __shfl_xor(z[i], 32, 64);
  }
  mi = max(mi, __shfl_xor(mi, 16, 64));
  mi = max(mi, __shfl_xor(mi, 32, 64));
  float zt = (z[0] + z[1]) + (z[2] + z[3]);
  float iz = 1.0f / zt;
  if (g == 0) invz[(size_t)bh * NQ + myrow] = iz;
  float ma = __builtin_amdgcn_exp2f((float)mi * alpha2) * iz;  // row softmax max
#pragma unroll
  for (int off = 1; off < 16; off <<= 1)
    ma = fmaxf(ma, __shfl_xor(ma, off, 64));
  if (lane == 0) mared[wave] = ma;
  __syncthreads();
  if (threadIdx.x == 0)
    atomicMax(scal + 3,
              __float_as_uint(fmaxf(fmaxf(mared[0], mared[1]),
                                    fmaxf(mared[2], mared[3]))));
}

// pass 2: waves split q-rows; k/v tiles in block LDS with T14 register
// prefetch; wave-private attn round-trip; exact int32 PV accumulation.
// PV MFMA operands swapped (exact integer sums, order-free) so D holds 4
// consecutive dims per lane -> packed 8B v4bf stores instead of 16x2B.
__global__ __launch_bounds__(256, 4) void k_pass2(
    const int8_t* __restrict__ q8, const int8_t* __restrict__ k8,
    const int8_t* __restrict__ v8t, const float* __restrict__ invz,
    const unsigned* __restrict__ scal, __bf16* __restrict__ o) {
  __shared__ __align__(16) int8_t kbuf[128 * 72];
  __shared__ __align__(16) int8_t vbuf[64 * 152];
  __shared__ __align__(16) int8_t albuf[4][16 * 152];
  int bh = blockIdx.y, b = bh >> 3, h = bh & 7;
  int wave = threadIdx.x >> 6, lane = threadIdx.x & 63;
  int l15 = lane & 15, g = lane >> 4;
  int row0 = blockIdx.x * 64;
  int myrow = row0 + wave * 16 + l15;
  const float aq = __uint_as_float(scal[0]), ak = __uint_as_float(scal[1]);
  const float avv = __uint_as_float(scal[2]), izm = __uint_as_float(scal[3]);
  const float alpha2 = (aq * ak) * (0.125f / (127.0f * 127.0f)) * 1.44269504f;
  const float oscale = (izm / 127.0f) * (avv / 127.0f);
  const float MAGIC = 12582912.0f;  // 1.5 * 2^23
  const v4i z4 = {0, 0, 0, 0};

  v4i qfrag = *(const v4i*)(q8 + (size_t)(b * NQ + myrow) * DMODEL + h * DH + g * 16);
  const float lcr = __builtin_amdgcn_logf(invz[(size_t)bh * NQ + myrow] * (127.0f / izm));
  const int8_t* kbase = k8 + (size_t)b * MK * DMODEL + h * DH;
  const int8_t* vbase = v8t + (size_t)bh * DH * MK;
  int8_t* alds = albuf[wave];
  const int rs = threadIdx.x >> 2, qs = (threadIdx.x & 3) * 16;
  const int vr = threadIdx.x >> 3, vq = (threadIdx.x & 7) * 16;
  const int8_t* kls = kbase + (size_t)rs * DMODEL + qs;
  const int8_t* vls = vbase + (size_t)vr * MK + vq;

  v4i kp0 = *(const v4i*)(kls);
  v4i kp1 = *(const v4i*)(kls + (size_t)64 * DMODEL);
  v4i vp0 = *(const v4i*)(vls);
  v4i vp1 = *(const v4i*)(vls + (size_t)32 * MK);

  v4i pacc[4] = {};
  for (int tile = 0; tile < 8; ++tile) {
    __syncthreads();
    *(v4i*)(&kbuf[rs * 72 + qs]) = kp0;
    *(v4i*)(&kbuf[(rs + 64) * 72 + qs]) = kp1;
    *(v4i*)(&vbuf[vr * 152 + vq]) = vp0;
    *(v4i*)(&vbuf[(vr + 32) * 152 + vq]) = vp1;
    __syncthreads();
    if (tile < 7) {  // prefetch next tile; hides under QK^T + softmax + PV
      kp0 = *(const v4i*)(kls + (size_t)((tile + 1) * 128) * DMODEL);
      kp1 = *(const v4i*)(kls + (size_t)((tile + 1) * 128 + 64) * DMODEL);
      vp0 = *(const v4i*)(vls + (tile + 1) * 128);
      vp1 = *(const v4i*)(vls + (size_t)32 * MK + (tile + 1) * 128);
    }
#pragma unroll
    for (int t = 0; t < 8; ++t) {
      v4i kfrag = *(const v4i*)(&kbuf[(t * 16 + l15) * 72 + g * 16]);
      v4i sa = __builtin_amdgcn_mfma_i32_16x16x64_i8(kfrag, qfrag, z4, 0, 0, 0);
      float f0 = __builtin_amdgcn_exp2f(fmaf((float)sa[0], alpha2, lcr)) + MAGIC;
      float f1 = __builtin_amdgcn_exp2f(fmaf((float)sa[1], alpha2, lcr)) + MAGIC;
      float f2 = __builtin_amdgcn_exp2f(fmaf((float)sa[2], alpha2, lcr)) + MAGIC;
      float f3 = __builtin_amdgcn_exp2f(fmaf((float)sa[3], alpha2, lcr)) + MAGIC;
      unsigned packed = (__float_as_uint(f0) & 255u) |
                        ((__float_as_uint(f1) & 255u) << 8) |
                        ((__float_as_uint(f2) & 255u) << 16) |
                        (__float_as_uint(f3) << 24);
      *(unsigned*)(alds + l15 * 152 + t * 16 + g * 4) = packed;
    }
#pragma unroll
    for (int c = 0; c < 2; ++c) {
      v4i afrag = *(const v4i*)(alds + l15 * 152 + c * 64 + g * 16);
#pragma unroll
      for (int d = 0; d < 4; ++d) {
        v4i vfrag = *(const v4i*)(&vbuf[(d * 16 + l15) * 152 + c * 64 + g * 16]);
        // swapped operands: D[dim][qrow] -> lane l15 = qrow, rows = dims
        pacc[d] = __builtin_amdgcn_mfma_i32_16x16x64_i8(vfrag, afrag, pacc[d], 0, 0, 0);
      }
    }
  }
  // D: col(l15)=qrow, row(g*4+r)=dim-within-16 -> 4 consecutive dims per lane
  __bf16* obase = o + (size_t)(b * NQ + row0 + wave * 16 + l15) * DMODEL + h * DH;
#pragma unroll
  for (int d = 0; d < 4; ++d) {
    v4bf ov;
#pragma unroll
    for (int r = 0; r < 4; ++r)
      ov[r] = (__bf16)((float)pacc[d][r] * oscale);
    *(v4bf*)(obase + d * 16 + g * 4) = ov;
  }
}

extern "C" void kernel_launch(void* const* d_in, const int* in_sizes, int n_in,
                              void* d_out, int out_size, void* d_ws, size_t ws_size,
                              hipStream_t stream) {
  (void)in_sizes; (void)n_in; (void)out_size; (void)ws_size;
  const float* x   = (const float*)d_in[0];
  const float* ctx = (const float*)d_in[1];
  const float* Wq  = (const float*)d_in[2];
  const float* Wk  = (const float*)d_in[3];
  const float* Wv  = (const float*)d_in[4];
  const float* Wo  = (const float*)d_in[5];
  const float* bo  = (const float*)d_in[6];
  float* out = (float*)d_out;

  char* ws = (char*)d_ws;
  size_t off = 0;
  auto alloc = [&](size_t bytes) {
    char* p = ws + off;
    off += (bytes + 255) & ~(size_t)255;
    return p;
  };
  unsigned* scal = (unsigned*)alloc(16);
  __bf16* Wq_t = (__bf16*)alloc((size_t)512 * 512 * 2);
  __bf16* Wk_t = (__bf16*)alloc((size_t)512 * 768 * 2);  // contiguous with Wv_t
  __bf16* Wv_t = (__bf16*)alloc((size_t)512 * 768 * 2);
  __bf16* Wo_t = (__bf16*)alloc((size_t)512 * 512 * 2);
  float* qf  = (float*)alloc((size_t)BATCH * NQ * DMODEL * 4);   // later reused as o
  float* kvf = (float*)alloc((size_t)BATCH * MK * 1024 * 4);     // [2048][1024]: k | v
  int8_t* q8 = (int8_t*)alloc((size_t)BATCH * NQ * DMODEL);
  int8_t* k8 = (int8_t*)alloc((size_t)BATCH * MK * DMODEL);
  int8_t* v8t = (int8_t*)alloc((size_t)BATCH * NH * DH * MK);
  float* invz = (float*)alloc((size_t)BATCH * NH * NQ * 4);
  __bf16* o = (__bf16*)qf;  // q_f32 dead after pass1 quantizes it

  k_prep<<<1536, 256, 0, stream>>>(Wq, Wk, Wv, Wo,
                                   Wq_t, Wk_t, Wv_t, Wo_t, scal);
  k_gemm_qkv<<<1024, 256, 0, stream>>>(x, Wq_t, qf, ctx, Wk_t, kvf, scal);
  k_quant_kv<<<1280, 256, 0, stream>>>(kvf, k8, v8t, scal);
  k_pass1<<<dim3(64, 16), 256, 0, stream>>>(qf, q8, k8, invz, scal);
  k_pass2<<<dim3(64, 16), 256, 0, stream>>>(q8, k8, v8t, invz, scal, o);
  k_gemm_out<<<512, 256, 0, stream>>>(o, Wo_t, out, bo);
}

// Round 2
// 193.485 us; speedup vs baseline: 1.0014x; 1.0014x over previous
//
#include <hip/hip_runtime.h>
#include <stdint.h>

typedef float  v4f  __attribute__((ext_vector_type(4)));
typedef int    v4i  __attribute__((ext_vector_type(4)));
typedef __bf16 v8bf __attribute__((ext_vector_type(8)));
typedef __bf16 v4bf __attribute__((ext_vector_type(4)));

#define BATCH  2
#define NQ     4096
#define MK     1024
#define DMODEL 512
#define DCTX   768
#define NH     8
#define DH     64

// Weights-only prep: 1536 blocks transpose weights to Wt[512][K] bf16.
// Block 0 zero-inits scal.
__global__ __launch_bounds__(256) void k_prep(
    const float* __restrict__ Wq, const float* __restrict__ Wk,
    const float* __restrict__ Wv, const float* __restrict__ Wo,
    __bf16* __restrict__ Wq_t, __bf16* __restrict__ Wk_t,
    __bf16* __restrict__ Wv_t, __bf16* __restrict__ Wo_t,
    unsigned* __restrict__ scal) {
  int id = blockIdx.x;
  if (id == 0 && threadIdx.x < 4) scal[threadIdx.x] = 0u;
  int tx = id & 15, rem = id >> 4;
  int ty = rem % 24, tz = rem / 24;
  const float* src; __bf16* dst; int K;
  switch (tz) {
    case 0:  src = Wq; dst = Wq_t; K = DMODEL; break;
    case 1:  src = Wk; dst = Wk_t; K = DCTX;   break;
    case 2:  src = Wv; dst = Wv_t; K = DCTX;   break;
    default: src = Wo; dst = Wo_t; K = DMODEL; break;
  }
  int k0 = ty * 32;
  if (k0 >= K) return;
  int n0 = tx * 32;
  __shared__ __bf16 tile[32][33];
  int c = threadIdx.x & 31, r0 = threadIdx.x >> 5;
  for (int i = 0; i < 4; ++i) {
    int r = r0 + i * 8;
    tile[c][r] = (__bf16)src[(size_t)(k0 + r) * DMODEL + n0 + c];
  }
  __syncthreads();
  for (int i = 0; i < 4; ++i) {
    int r = r0 + i * 8;
    dst[(size_t)(n0 + r) * K + k0 + c] = tile[r][c];
  }
}

// A-fragment loaders: bf16 direct, or fp32 with inline RNE cvt (bit-identical
// to a bf16 prep-staging path).
__device__ __forceinline__ v8bf load_a8(const __bf16* p) {
  return *(const v8bf*)p;
}
__device__ __forceinline__ v8bf load_a8(const float* p) {
  float4 a = *(const float4*)p, b = *(const float4*)(p + 4);
  v8bf o = { (__bf16)a.x, (__bf16)a.y, (__bf16)a.z, (__bf16)a.w,
             (__bf16)b.x, (__bf16)b.y, (__bf16)b.z, (__bf16)b.w };
  return o;
}

// B-stationary GEMM body: C[.][N] tile = A[128 rows][K_] @ Bt[NC cols][K_]^T.
// NC-col B panel for ALL K in LDS (one barrier); K-loop barrier-free.
// Per-element k-ascending MFMA chain identical for any NC -> bit-identical C.
template<int K_, int NC, bool BIAS, bool AMAX, typename AT>
__device__ __forceinline__ void gemm_body(
    char* smemraw, const AT* __restrict__ A, const __bf16* __restrict__ Bt,
    float* __restrict__ C, int N, int rowBlk, int colBlk,
    const float* __restrict__ bias,
    unsigned* __restrict__ amaxLo, unsigned* __restrict__ amaxHi) {
  constexpr int CS = K_ + 8;
  constexpr int GPC = K_ / 8;
  constexpr int JT = NC / 16;
  __bf16* Bs = (__bf16*)smemraw;
  float* redmax = (float*)(smemraw + (size_t)NC * CS * 2);
  const int tid = threadIdx.x;
  const int lane = tid & 63, wave = tid >> 6;
  const int l15 = lane & 15, g = lane >> 4;
  const int col0 = colBlk * NC;
  const int row0w = rowBlk * 128 + wave * 32;

#pragma unroll
  for (int i = 0; i < NC * GPC / 256; ++i) {
    int f = i * 256 + tid;
    int c = f / GPC, w = f - c * GPC;
    *(v8bf*)(&Bs[c * CS + w * 8]) =
        *(const v8bf*)(Bt + (size_t)(col0 + c) * K_ + w * 8);
  }
  __syncthreads();

  v4f acc[2][JT] = {};
  const AT* a0 = A + (size_t)(row0w + l15) * K_ + g * 8;
  const AT* a1 = A + (size_t)(row0w + 16 + l15) * K_ + g * 8;
#pragma unroll
  for (int k0 = 0; k0 < K_; k0 += 32) {
    v8bf af0 = load_a8(a0 + k0);
    v8bf af1 = load_a8(a1 + k0);
#pragma unroll
    for (int j = 0; j < JT; ++j) {
      v8bf bfj = *(const v8bf*)(&Bs[(j * 16 + l15) * CS + k0 + g * 8]);
      acc[0][j] = __builtin_amdgcn_mfma_f32_16x16x32_bf16(af0, bfj, acc[0][j], 0, 0, 0);
      acc[1][j] = __builtin_amdgcn_mfma_f32_16x16x32_bf16(af1, bfj, acc[1][j], 0, 0, 0);
    }
  }

  float lmax = 0.0f;
#pragma unroll
  for (int j = 0; j < JT; ++j) {
    int col = col0 + j * 16 + l15;
    float bv = BIAS ? bias[col] : 0.0f;
#pragma unroll
    for (int i = 0; i < 2; ++i) {
#pragma unroll
      for (int r = 0; r < 4; ++r) {
        int row = row0w + i * 16 + g * 4 + r;  // C/D: col=lane&15, row=quad*4+reg
        float cv = acc[i][j][r] + bv;
        C[(size_t)row * N + col] = cv;
        if (AMAX) lmax = fmaxf(lmax, fabsf(cv));
      }
    }
  }
  if (AMAX) {
    for (int off = 32; off > 0; off >>= 1)
      lmax = fmaxf(lmax, __shfl_xor(lmax, off, 64));
    if (lane == 0) redmax[wave] = lmax;
    __syncthreads();
    if (tid == 0) {
      float bm = fmaxf(fmaxf(redmax[0], redmax[1]), fmaxf(redmax[2], redmax[3]));
      atomicMax(col0 < 512 ? amaxLo : amaxHi, __float_as_uint(bm));
    }
  }
}

// Fused projections with XCD-aware work assignment: with round-robin
// dispatch, xcd = bid % 8. All column-panels of one A row-panel are assigned
// to blocks with the SAME bid%8 (= same XCD L2), and are temporally adjacent
// within that XCD -> the A panel is HBM-fetched once and L2-hit 7x (q) /
// 31x (kv) instead of being re-fetched by every XCD.
__global__ __launch_bounds__(256, 2) void k_gemm_qkv(
    const float* __restrict__ x, const __bf16* __restrict__ Wq_t,
    float* __restrict__ qf,
    const float* __restrict__ ctx, const __bf16* __restrict__ Wkv_t,
    float* __restrict__ kvf, unsigned* __restrict__ scal) {
  __shared__ __align__(16) char smem[64 * (512 + 8) * 2 + 16];
  int bid = blockIdx.x;
  if (bid < 512) {
    // q: 64 rowBlks x 8 colBlks. xcd owns rowBlks [xcd*8, xcd*8+8).
    int xcd = bid & 7, w = bid >> 3;
    gemm_body<512, 64, false, true, float>(smem, x, Wq_t, qf, 512,
                                           xcd * 8 + (w >> 3), w & 7, nullptr,
                                           scal + 0, scal + 0);
  } else {
    // kv: 16 rowBlks x 32 colBlks. xcd owns rowBlks [xcd*2, xcd*2+2).
    int id = bid - 512;           // 512 % 8 == 0 -> id%8 still == bid%8
    int xcd = id & 7, w = id >> 3;
    gemm_body<768, 32, false, true, float>(smem, ctx, Wkv_t, kvf, 1024,
                                           xcd * 2 + (w >> 5), w & 31, nullptr,
                                           scal + 1, scal + 2);
  }
}

__global__ __launch_bounds__(256, 2) void k_gemm_out(
    const __bf16* __restrict__ o, const __bf16* __restrict__ Wo_t,
    float* __restrict__ out, const float* __restrict__ bo) {
  __shared__ __align__(16) char smem[64 * (512 + 8) * 2 + 16];
  int xcd = blockIdx.x & 7, w = blockIdx.x >> 3;
  gemm_body<512, 64, true, false, __bf16>(smem, o, Wo_t, out, 512,
                                          xcd * 8 + (w >> 3), w & 7, bo,
                                          nullptr, nullptr);
}

// k/v quantization: blocks [0,1024) quantize k; [1024,1280) transpose-quantize v.
__global__ __launch_bounds__(256) void k_quant_kv(
    const float* __restrict__ kvf,
    int8_t* __restrict__ k8, int8_t* __restrict__ v8t,
    const unsigned* __restrict__ scal) {
  __shared__ int8_t tile[64][80];
  int bx = blockIdx.x;
  if (bx < 1024) {
    int j = bx * 256 + threadIdx.x;
    int r = j >> 7;
    int c4 = (j & 127) << 2;
    float4 v = *(const float4*)(kvf + (size_t)r * 1024 + c4);
    float s = 127.0f / __uint_as_float(scal[1]);
    int a0 = __float2int_rn(v.x * s), a1 = __float2int_rn(v.y * s);
    int a2 = __float2int_rn(v.z * s), a3 = __float2int_rn(v.w * s);
    a0 = max(-128, min(127, a0)); a1 = max(-128, min(127, a1));
    a2 = max(-128, min(127, a2)); a3 = max(-128, min(127, a3));
    unsigned p = (unsigned)(a0 & 255) | ((unsigned)(a1 & 255) << 8) |
                 ((unsigned)(a2 & 255) << 16) | ((unsigned)(a3 & 255) << 24);
    *(unsigned*)(k8 + (size_t)j * 4) = p;
    return;
  }
  int id = bx - 1024;
  int bh = id >> 4, b = bh >> 3, h = bh & 7;
  int j0 = (id & 15) * 64;
  const float s = 127.0f / __uint_as_float(scal[2]);
  int t = threadIdx.x;
  int j = t >> 2, dh0 = (t & 3) << 4;
  const float* src = kvf + (size_t)(b * MK + j0 + j) * 1024 + 512 + h * DH + dh0;
#pragma unroll
  for (int i = 0; i < 16; i += 4) {
    float4 v = *(const float4*)(src + i);
    int a0 = __float2int_rn(v.x * s), a1 = __float2int_rn(v.y * s);
    int a2 = __float2int_rn(v.z * s), a3 = __float2int_rn(v.w * s);
    tile[dh0 + i + 0][j] = (int8_t)max(-128, min(127, a0));
    tile[dh0 + i + 1][j] = (int8_t)max(-128, min(127, a1));
    tile[dh0 + i + 2][j] = (int8_t)max(-128, min(127, a2));
    tile[dh0 + i + 3][j] = (int8_t)max(-128, min(127, a3));
  }
  __syncthreads();
  int dh = t >> 2, jb = (t & 3) << 4;
  v4i val = *(const v4i*)(&tile[dh][jb]);
  *(v4i*)(v8t + (size_t)(bh * DH + dh) * MK + j0 + jb) = val;
}

__device__ __forceinline__ v4i quant_pack16(const float* p, float s) {
  v4i out;
#pragma unroll
  for (int q = 0; q < 4; ++q) {
    float4 v = *(const float4*)(p + q * 4);
    int a0 = __float2int_rn(v.x * s), a1 = __float2int_rn(v.y * s);
    int a2 = __float2int_rn(v.z * s), a3 = __float2int_rn(v.w * s);
    a0 = max(-128, min(127, a0)); a1 = max(-128, min(127, a1));
    a2 = max(-128, min(127, a2)); a3 = max(-128, min(127, a3));
    out[q] = (int)((unsigned)(a0 & 255) | ((unsigned)(a1 & 255) << 8) |
                   ((unsigned)(a2 & 255) << 16) | ((unsigned)(a3 & 255) << 24));
  }
  return out;
}

// pass 1: waves split q-rows (16 each); 8 tiles of 128 keys staged in LDS.
// T14 prefetch: next tile's K loaded into registers during compute, ds_write
// after the barrier. z summation tree unchanged -> bit-identical invz.
__global__ __launch_bounds__(256, 4) void k_pass1(
    const float* __restrict__ qf, int8_t* __restrict__ q8,
    const int8_t* __restrict__ k8,
    float* __restrict__ invz, unsigned* __restrict__ scal) {
  __shared__ __align__(16) int8_t kbuf[128 * 72];
  __shared__ float mared[4];
  int bh = blockIdx.y, b = bh >> 3, h = bh & 7;
  int wave = threadIdx.x >> 6, lane = threadIdx.x & 63;
  int l15 = lane & 15, g = lane >> 4;
  int row0 = blockIdx.x * 64;
  int myrow = row0 + wave * 16 + l15;
  const float aq = __uint_as_float(scal[0]), ak = __uint_as_float(scal[1]);
  const float alpha2 = (aq * ak) * (0.125f / (127.0f * 127.0f)) * 1.44269504f;
  const float sq = 127.0f / aq;
  const v4i z4 = {0, 0, 0, 0};
  size_t qoff = (size_t)(b * NQ + myrow) * DMODEL + h * DH + g * 16;
  v4i qfrag = quant_pack16(qf + qoff, sq);
  *(v4i*)(q8 + qoff) = qfrag;
  const int8_t* kbase = k8 + (size_t)b * MK * DMODEL + h * DH;
  const int rs = threadIdx.x >> 2, qs = (threadIdx.x & 3) * 16;
  const int8_t* kls = kbase + (size_t)rs * DMODEL + qs;

  v4i kp0 = *(const v4i*)(kls);
  v4i kp1 = *(const v4i*)(kls + (size_t)64 * DMODEL);

  float z[4] = {0.f, 0.f, 0.f, 0.f};
  int mi = -(1 << 30);
  for (int tile = 0; tile < 8; ++tile) {
    __syncthreads();
    *(v4i*)(&kbuf[rs * 72 + qs]) = kp0;
    *(v4i*)(&kbuf[(rs + 64) * 72 + qs]) = kp1;
    __syncthreads();
    if (tile < 7) {  // prefetch next tile; latency hides under compute below
      kp0 = *(const v4i*)(kls + (size_t)((tile + 1) * 128) * DMODEL);
      kp1 = *(const v4i*)(kls + (size_t)((tile + 1) * 128 + 64) * DMODEL);
    }
    float zt = z[tile >> 1];
#pragma unroll
    for (int t = 0; t < 8; ++t) {
      v4i kfrag = *(const v4i*)(&kbuf[(t * 16 + l15) * 72 + g * 16]);
      v4i sa = __builtin_amdgcn_mfma_i32_16x16x64_i8(kfrag, qfrag, z4, 0, 0, 0);
      mi = max(mi, max(max(sa[0], sa[1]), max(sa[2], sa[3])));
      float e0 = __builtin_amdgcn_exp2f((float)sa[0] * alpha2);
      float e1 = __builtin_amdgcn_exp2f((float)sa[1] * alpha2);
      float e2 = __builtin_amdgcn_exp2f((float)sa[2] * alpha2);
      float e3 = __builtin_amdgcn_exp2f((float)sa[3] * alpha2);
      zt += (e0 + e1) + (e2 + e3);
    }
    z[tile >> 1] = zt;
  }
#pragma unroll
  for (int i = 0; i < 4; ++i) {
    z[i] += __shfl_xor(z[i], 16, 64);
    z[i] += __shfl_xor(z[i], 32, 64);
  }
  mi = max(mi, __shfl_xor(mi, 16, 64));
  mi = max(mi, __shfl_xor(mi, 32, 64));
  float zt = (z[0] + z[1]) + (z[2] + z[3]);
  float iz = 1.0f / zt;
  if (g == 0) invz[(size_t)bh * NQ + myrow] = iz;
  float ma = __builtin_amdgcn_exp2f((float)mi * alpha2) * iz;  // row softmax max
#pragma unroll
  for (int off = 1; off < 16; off <<= 1)
    ma = fmaxf(ma, __shfl_xor(ma, off, 64));
  if (lane == 0) mared[wave] = ma;
  __syncthreads();
  if (threadIdx.x == 0)
    atomicMax(scal + 3,
              __float_as_uint(fmaxf(fmaxf(mared[0], mared[1]),
                                    fmaxf(mared[2], mared[3]))));
}

// pass 2: waves split q-rows; k/v tiles in block LDS with T14 register
// prefetch; wave-private attn round-trip; exact int32 PV accumulation.
// PV MFMA operands swapped (exact integer sums, order-free) so D holds 4
// consecutive dims per lane -> packed 8B v4bf stores instead of 16x2B.
__global__ __launch_bounds__(256, 4) void k_pass2(
    const int8_t* __restrict__ q8, const int8_t* __restrict__ k8,
    const int8_t* __restrict__ v8t, const float* __restrict__ invz,
    const unsigned* __restrict__ scal, __bf16* __restrict__ o) {
  __shared__ __align__(16) int8_t kbuf[128 * 72];
  __shared__ __align__(16) int8_t vbuf[64 * 152];
  __shared__ __align__(16) int8_t albuf[4][16 * 152];
  int bh = blockIdx.y, b = bh >> 3, h = bh & 7;
  int wave = threadIdx.x >> 6, lane = threadIdx.x & 63;
  int l15 = lane & 15, g = lane >> 4;
  int row0 = blockIdx.x * 64;
  int myrow = row0 + wave * 16 + l15;
  const float aq = __uint_as_float(scal[0]), ak = __uint_as_float(scal[1]);
  const float avv = __uint_as_float(scal[2]), izm = __uint_as_float(scal[3]);
  const float alpha2 = (aq * ak) * (0.125f / (127.0f * 127.0f)) * 1.44269504f;
  const float oscale = (izm / 127.0f) * (avv / 127.0f);
  const float MAGIC = 12582912.0f;  // 1.5 * 2^23
  const v4i z4 = {0, 0, 0, 0};

  v4i qfrag = *(const v4i*)(q8 + (size_t)(b * NQ + myrow) * DMODEL + h * DH + g * 16);
  const float lcr = __builtin_amdgcn_logf(invz[(size_t)bh * NQ + myrow] * (127.0f / izm));
  const int8_t* kbase = k8 + (size_t)b * MK * DMODEL + h * DH;
  const int8_t* vbase = v8t + (size_t)bh * DH * MK;
  int8_t* alds = albuf[wave];
  const int rs = threadIdx.x >> 2, qs = (threadIdx.x & 3) * 16;
  const int vr = threadIdx.x >> 3, vq = (threadIdx.x & 7) * 16;
  const int8_t* kls = kbase + (size_t)rs * DMODEL + qs;
  const int8_t* vls = vbase + (size_t)vr * MK + vq;

  v4i kp0 = *(const v4i*)(kls);
  v4i kp1 = *(const v4i*)(kls + (size_t)64 * DMODEL);
  v4i vp0 = *(const v4i*)(vls);
  v4i vp1 = *(const v4i*)(vls + (size_t)32 * MK);

  v4i pacc[4] = {};
  for (int tile = 0; tile < 8; ++tile) {
    __syncthreads();
    *(v4i*)(&kbuf[rs * 72 + qs]) = kp0;
    *(v4i*)(&kbuf[(rs + 64) * 72 + qs]) = kp1;
    *(v4i*)(&vbuf[vr * 152 + vq]) = vp0;
    *(v4i*)(&vbuf[(vr + 32) * 152 + vq]) = vp1;
    __syncthreads();
    if (tile < 7) {  // prefetch next tile; hides under QK^T + softmax + PV
      kp0 = *(const v4i*)(kls + (size_t)((tile + 1) * 128) * DMODEL);
      kp1 = *(const v4i*)(kls + (size_t)((tile + 1) * 128 + 64) * DMODEL);
      vp0 = *(const v4i*)(vls + (tile + 1) * 128);
      vp1 = *(const v4i*)(vls + (size_t)32 * MK + (tile + 1) * 128);
    }
#pragma unroll
    for (int t = 0; t < 8; ++t) {
      v4i kfrag = *(const v4i*)(&kbuf[(t * 16 + l15) * 72 + g * 16]);
      v4i sa = __builtin_amdgcn_mfma_i32_16x16x64_i8(kfrag, qfrag, z4, 0, 0, 0);
      float f0 = __builtin_amdgcn_exp2f(fmaf((float)sa[0], alpha2, lcr)) + MAGIC;
      float f1 = __builtin_amdgcn_exp2f(fmaf((float)sa[1], alpha2, lcr)) + MAGIC;
      float f2 = __builtin_amdgcn_exp2f(fmaf((float)sa[2], alpha2, lcr)) + MAGIC;
      float f3 = __builtin_amdgcn_exp2f(fmaf((float)sa[3], alpha2, lcr)) + MAGIC;
      unsigned packed = (__float_as_uint(f0) & 255u) |
                        ((__float_as_uint(f1) & 255u) << 8) |
                        ((__float_as_uint(f2) & 255u) << 16) |
                        (__float_as_uint(f3) << 24);
      *(unsigned*)(alds + l15 * 152 + t * 16 + g * 4) = packed;
    }
#pragma unroll
    for (int c = 0; c < 2; ++c) {
      v4i afrag = *(const v4i*)(alds + l15 * 152 + c * 64 + g * 16);
#pragma unroll
      for (int d = 0; d < 4; ++d) {
        v4i vfrag = *(const v4i*)(&vbuf[(d * 16 + l15) * 152 + c * 64 + g * 16]);
        // swapped operands: D[dim][qrow] -> lane l15 = qrow, rows = dims
        pacc[d] = __builtin_amdgcn_mfma_i32_16x16x64_i8(vfrag, afrag, pacc[d], 0, 0, 0);
      }
    }
  }
  // D: col(l15)=qrow, row(g*4+r)=dim-within-16 -> 4 consecutive dims per lane
  __bf16* obase = o + (size_t)(b * NQ + row0 + wave * 16 + l15) * DMODEL + h * DH;
#pragma unroll
  for (int d = 0; d < 4; ++d) {
    v4bf ov;
#pragma unroll
    for (int r = 0; r < 4; ++r)
      ov[r] = (__bf16)((float)pacc[d][r] * oscale);
    *(v4bf*)(obase + d * 16 + g * 4) = ov;
  }
}

extern "C" void kernel_launch(void* const* d_in, const int* in_sizes, int n_in,
                              void* d_out, int out_size, void* d_ws, size_t ws_size,
                              hipStream_t stream) {
  (void)in_sizes; (void)n_in; (void)out_size; (void)ws_size;
  const float* x   = (const float*)d_in[0];
  const float* ctx = (const float*)d_in[1];
  const float* Wq  = (const float*)d_in[2];
  const float* Wk  = (const float*)d_in[3];
  const float* Wv  = (const float*)d_in[4];
  const float* Wo  = (const float*)d_in[5];
  const float* bo  = (const float*)d_in[6];
  float* out = (float*)d_out;

  char* ws = (char*)d_ws;
  size_t off = 0;
  auto alloc = [&](size_t bytes) {
    char* p = ws + off;
    off += (bytes + 255) & ~(size_t)255;
    return p;
  };
  unsigned* scal = (unsigned*)alloc(16);
  __bf16* Wq_t = (__bf16*)alloc((size_t)512 * 512 * 2);
  __bf16* Wk_t = (__bf16*)alloc((size_t)512 * 768 * 2);  // contiguous with Wv_t
  __bf16* Wv_t = (__bf16*)alloc((size_t)512 * 768 * 2);
  __bf16* Wo_t = (__bf16*)alloc((size_t)512 * 512 * 2);
  float* qf  = (float*)alloc((size_t)BATCH * NQ * DMODEL * 4);   // later reused as o
  float* kvf = (float*)alloc((size_t)BATCH * MK * 1024 * 4);     // [2048][1024]: k | v
  int8_t* q8 = (int8_t*)alloc((size_t)BATCH * NQ * DMODEL);
  int8_t* k8 = (int8_t*)alloc((size_t)BATCH * MK * DMODEL);
  int8_t* v8t = (int8_t*)alloc((size_t)BATCH * NH * DH * MK);
  float* invz = (float*)alloc((size_t)BATCH * NH * NQ * 4);
  __bf16* o = (__bf16*)qf;  // q_f32 dead after pass1 quantizes it

  k_prep<<<1536, 256, 0, stream>>>(Wq, Wk, Wv, Wo,
                                   Wq_t, Wk_t, Wv_t, Wo_t, scal);
  k_gemm_qkv<<<1024, 256, 0, stream>>>(x, Wq_t, qf, ctx, Wk_t, kvf, scal);
  k_quant_kv<<<1280, 256, 0, stream>>>(kvf, k8, v8t, scal);
  k_pass1<<<dim3(64, 16), 256, 0, stream>>>(qf, q8, k8, invz, scal);
  k_pass2<<<dim3(64, 16), 256, 0, stream>>>(q8, k8, v8t, invz, scal, o);
  k_gemm_out<<<512, 256, 0, stream>>>(o, Wo_t, out, bo);
}

// Round 3
// 177.954 us; speedup vs baseline: 1.0888x; 1.0873x over previous
//
#include <hip/hip_runtime.h>
#include <stdint.h>

typedef float  v4f  __attribute__((ext_vector_type(4)));
typedef int    v4i  __attribute__((ext_vector_type(4)));
typedef __bf16 v8bf __attribute__((ext_vector_type(8)));
typedef __bf16 v4bf __attribute__((ext_vector_type(4)));

#define BATCH  2
#define NQ     4096
#define MK     1024
#define DMODEL 512
#define DCTX   768
#define NH     8
#define DH     64

// Merged prep: blocks [0,2816) convert x/ctx fp32->bf16 (RNE -> bits identical
// to inline-cvt GEMM path); blocks [2816,4352) transpose weights to
// Wt[512][K] bf16. Block 2816 zero-inits scal.
__global__ __launch_bounds__(256) void k_prep(
    const float* __restrict__ x, const float* __restrict__ ctx,
    __bf16* __restrict__ xb, __bf16* __restrict__ cb,
    const float* __restrict__ Wq, const float* __restrict__ Wk,
    const float* __restrict__ Wv, const float* __restrict__ Wo,
    __bf16* __restrict__ Wq_t, __bf16* __restrict__ Wk_t,
    __bf16* __restrict__ Wv_t, __bf16* __restrict__ Wo_t,
    unsigned* __restrict__ scal) {
  int bx = blockIdx.x;
  if (bx < 2816) {
    const int XC = BATCH * NQ * DMODEL / 8;
    const int CC = BATCH * MK * DCTX / 8;
    int idx = bx * 256 + threadIdx.x;
    const float* src; __bf16* dst;
    if (idx < XC) { src = x + (size_t)idx * 8; dst = xb + (size_t)idx * 8; }
    else {
      int j = idx - XC;
      if (j >= CC) return;
      src = ctx + (size_t)j * 8; dst = cb + (size_t)j * 8;
    }
    float4 a = *(const float4*)src, b = *(const float4*)(src + 4);
    v8bf o = { (__bf16)a.x, (__bf16)a.y, (__bf16)a.z, (__bf16)a.w,
               (__bf16)b.x, (__bf16)b.y, (__bf16)b.z, (__bf16)b.w };
    *(v8bf*)dst = o;
    return;
  }
  int id = bx - 2816;
  if (id == 0 && threadIdx.x < 4) scal[threadIdx.x] = 0u;
  int tx = id & 15, rem = id >> 4;
  int ty = rem % 24, tz = rem / 24;
  const float* src; __bf16* dst; int K;
  switch (tz) {
    case 0:  src = Wq; dst = Wq_t; K = DMODEL; break;
    case 1:  src = Wk; dst = Wk_t; K = DCTX;   break;
    case 2:  src = Wv; dst = Wv_t; K = DCTX;   break;
    default: src = Wo; dst = Wo_t; K = DMODEL; break;
  }
  int k0 = ty * 32;
  if (k0 >= K) return;
  int n0 = tx * 32;
  __shared__ __bf16 tile[32][33];
  int c = threadIdx.x & 31, r0 = threadIdx.x >> 5;
  for (int i = 0; i < 4; ++i) {
    int r = r0 + i * 8;
    tile[c][r] = (__bf16)src[(size_t)(k0 + r) * DMODEL + n0 + c];
  }
  __syncthreads();
  for (int i = 0; i < 4; ++i) {
    int r = r0 + i * 8;
    dst[(size_t)(n0 + r) * K + k0 + c] = tile[r][c];
  }
}

// B-stationary GEMM body: C[.][N] tile = A[128 rows][K_] @ Bt[NC cols][K_]^T.
// NC-col B panel for ALL K in LDS (one barrier); K-loop barrier-free.
// Latency fix (r3): depth-4 A-fragment register prefetch + double-buffered
// B ds_reads -- all buffers statically indexed under full unroll (rule #20).
// Per-element k-ascending MFMA chain unchanged -> bit-identical C.
template<int K_, int NC, bool BIAS, bool AMAX>
__device__ __forceinline__ void gemm_body(
    char* smemraw, const __bf16* __restrict__ A, const __bf16* __restrict__ Bt,
    float* __restrict__ C, int N, int rowBlk, int colBlk,
    const float* __restrict__ bias,
    unsigned* __restrict__ amaxLo, unsigned* __restrict__ amaxHi) {
  constexpr int CS = K_ + 8;
  constexpr int GPC = K_ / 8;
  constexpr int JT = NC / 16;
  constexpr int NIT = K_ / 32;
  constexpr int AD = 4;  // A prefetch depth (NIT % AD == 0 for K=512/768)
  __bf16* Bs = (__bf16*)smemraw;
  float* redmax = (float*)(smemraw + (size_t)NC * CS * 2);
  const int tid = threadIdx.x;
  const int lane = tid & 63, wave = tid >> 6;
  const int l15 = lane & 15, g = lane >> 4;
  const int col0 = colBlk * NC;
  const int row0w = rowBlk * 128 + wave * 32;

#pragma unroll
  for (int i = 0; i < NC * GPC / 256; ++i) {
    int f = i * 256 + tid;
    int c = f / GPC, w = f - c * GPC;
    *(v8bf*)(&Bs[c * CS + w * 8]) =
        *(const v8bf*)(Bt + (size_t)(col0 + c) * K_ + w * 8);
  }

  const __bf16* a0 = A + (size_t)(row0w + l15) * K_ + g * 8;
  const __bf16* a1 = A + (size_t)(row0w + 16 + l15) * K_ + g * 8;

  // prologue A prefetch: independent of LDS, overlaps the staging barrier
  v8bf abuf0[AD], abuf1[AD];
#pragma unroll
  for (int i = 0; i < AD; ++i) {
    abuf0[i] = *(const v8bf*)(a0 + i * 32);
    abuf1[i] = *(const v8bf*)(a1 + i * 32);
  }
  __syncthreads();

  v8bf bbuf[2][JT];
#pragma unroll
  for (int j = 0; j < JT; ++j)
    bbuf[0][j] = *(const v8bf*)(&Bs[(j * 16 + l15) * CS + g * 8]);

  v4f acc[2][JT] = {};
#pragma unroll
  for (int it = 0; it < NIT; ++it) {
    const int cur = it & 1, nxt = cur ^ 1;
    if (it + 1 < NIT) {
#pragma unroll
      for (int j = 0; j < JT; ++j)
        bbuf[nxt][j] =
            *(const v8bf*)(&Bs[(j * 16 + l15) * CS + (it + 1) * 32 + g * 8]);
    }
    v8bf af0 = abuf0[it % AD];
    v8bf af1 = abuf1[it % AD];
    if (it + AD < NIT) {  // refill slot for iteration it+AD
      abuf0[it % AD] = *(const v8bf*)(a0 + (it + AD) * 32);
      abuf1[it % AD] = *(const v8bf*)(a1 + (it + AD) * 32);
    }
#pragma unroll
    for (int j = 0; j < JT; ++j) {
      acc[0][j] = __builtin_amdgcn_mfma_f32_16x16x32_bf16(af0, bbuf[cur][j], acc[0][j], 0, 0, 0);
      acc[1][j] = __builtin_amdgcn_mfma_f32_16x16x32_bf16(af1, bbuf[cur][j], acc[1][j], 0, 0, 0);
    }
  }

  float lmax = 0.0f;
#pragma unroll
  for (int j = 0; j < JT; ++j) {
    int col = col0 + j * 16 + l15;
    float bv = BIAS ? bias[col] : 0.0f;
#pragma unroll
    for (int i = 0; i < 2; ++i) {
#pragma unroll
      for (int r = 0; r < 4; ++r) {
        int row = row0w + i * 16 + g * 4 + r;  // C/D: col=lane&15, row=quad*4+reg
        float cv = acc[i][j][r] + bv;
        C[(size_t)row * N + col] = cv;
        if (AMAX) lmax = fmaxf(lmax, fabsf(cv));
      }
    }
  }
  if (AMAX) {
    for (int off = 32; off > 0; off >>= 1)
      lmax = fmaxf(lmax, __shfl_xor(lmax, off, 64));
    if (lane == 0) redmax[wave] = lmax;
    __syncthreads();
    if (tid == 0) {
      float bm = fmaxf(fmaxf(redmax[0], redmax[1]), fmaxf(redmax[2], redmax[3]));
      atomicMax(col0 < 512 ? amaxLo : amaxHi, __float_as_uint(bm));
    }
  }
}

// Fused projections with XCD-aware work assignment (r2, proven on FETCH):
// all column-panels of one A row-panel land on the same XCD L2.
__global__ __launch_bounds__(256, 2) void k_gemm_qkv(
    const __bf16* __restrict__ xb, const __bf16* __restrict__ Wq_t,
    float* __restrict__ qf,
    const __bf16* __restrict__ cb, const __bf16* __restrict__ Wkv_t,
    float* __restrict__ kvf, unsigned* __restrict__ scal) {
  __shared__ __align__(16) char smem[64 * (512 + 8) * 2 + 16];
  int bid = blockIdx.x;
  if (bid < 512) {
    // q: 64 rowBlks x 8 colBlks. xcd owns rowBlks [xcd*8, xcd*8+8).
    int xcd = bid & 7, w = bid >> 3;
    gemm_body<512, 64, false, true>(smem, xb, Wq_t, qf, 512,
                                    xcd * 8 + (w >> 3), w & 7, nullptr,
                                    scal + 0, scal + 0);
  } else {
    // kv: 16 rowBlks x 32 colBlks. xcd owns rowBlks [xcd*2, xcd*2+2).
    int id = bid - 512;
    int xcd = id & 7, w = id >> 3;
    gemm_body<768, 32, false, true>(smem, cb, Wkv_t, kvf, 1024,
                                    xcd * 2 + (w >> 5), w & 31, nullptr,
                                    scal + 1, scal + 2);
  }
}

__global__ __launch_bounds__(256, 2) void k_gemm_out(
    const __bf16* __restrict__ o, const __bf16* __restrict__ Wo_t,
    float* __restrict__ out, const float* __restrict__ bo) {
  __shared__ __align__(16) char smem[64 * (512 + 8) * 2 + 16];
  int xcd = blockIdx.x & 7, w = blockIdx.x >> 3;
  gemm_body<512, 64, true, false>(smem, o, Wo_t, out, 512,
                                  xcd * 8 + (w >> 3), w & 7, bo,
                                  nullptr, nullptr);
}

// k/v quantization: blocks [0,1024) quantize k; [1024,1280) transpose-quantize v.
__global__ __launch_bounds__(256) void k_quant_kv(
    const float* __restrict__ kvf,
    int8_t* __restrict__ k8, int8_t* __restrict__ v8t,
    const unsigned* __restrict__ scal) {
  __shared__ int8_t tile[64][80];
  int bx = blockIdx.x;
  if (bx < 1024) {
    int j = bx * 256 + threadIdx.x;
    int r = j >> 7;
    int c4 = (j & 127) << 2;
    float4 v = *(const float4*)(kvf + (size_t)r * 1024 + c4);
    float s = 127.0f / __uint_as_float(scal[1]);
    int a0 = __float2int_rn(v.x * s), a1 = __float2int_rn(v.y * s);
    int a2 = __float2int_rn(v.z * s), a3 = __float2int_rn(v.w * s);
    a0 = max(-128, min(127, a0)); a1 = max(-128, min(127, a1));
    a2 = max(-128, min(127, a2)); a3 = max(-128, min(127, a3));
    unsigned p = (unsigned)(a0 & 255) | ((unsigned)(a1 & 255) << 8) |
                 ((unsigned)(a2 & 255) << 16) | ((unsigned)(a3 & 255) << 24);
    *(unsigned*)(k8 + (size_t)j * 4) = p;
    return;
  }
  int id = bx - 1024;
  int bh = id >> 4, b = bh >> 3, h = bh & 7;
  int j0 = (id & 15) * 64;
  const float s = 127.0f / __uint_as_float(scal[2]);
  int t = threadIdx.x;
  int j = t >> 2, dh0 = (t & 3) << 4;
  const float* src = kvf + (size_t)(b * MK + j0 + j) * 1024 + 512 + h * DH + dh0;
#pragma unroll
  for (int i = 0; i < 16; i += 4) {
    float4 v = *(const float4*)(src + i);
    int a0 = __float2int_rn(v.x * s), a1 = __float2int_rn(v.y * s);
    int a2 = __float2int_rn(v.z * s), a3 = __float2int_rn(v.w * s);
    tile[dh0 + i + 0][j] = (int8_t)max(-128, min(127, a0));
    tile[dh0 + i + 1][j] = (int8_t)max(-128, min(127, a1));
    tile[dh0 + i + 2][j] = (int8_t)max(-128, min(127, a2));
    tile[dh0 + i + 3][j] = (int8_t)max(-128, min(127, a3));
  }
  __syncthreads();
  int dh = t >> 2, jb = (t & 3) << 4;
  v4i val = *(const v4i*)(&tile[dh][jb]);
  *(v4i*)(v8t + (size_t)(bh * DH + dh) * MK + j0 + jb) = val;
}

__device__ __forceinline__ v4i quant_pack16(const float* p, float s) {
  v4i out;
#pragma unroll
  for (int q = 0; q < 4; ++q) {
    float4 v = *(const float4*)(p + q * 4);
    int a0 = __float2int_rn(v.x * s), a1 = __float2int_rn(v.y * s);
    int a2 = __float2int_rn(v.z * s), a3 = __float2int_rn(v.w * s);
    a0 = max(-128, min(127, a0)); a1 = max(-128, min(127, a1));
    a2 = max(-128, min(127, a2)); a3 = max(-128, min(127, a3));
    out[q] = (int)((unsigned)(a0 & 255) | ((unsigned)(a1 & 255) << 8) |
                   ((unsigned)(a2 & 255) << 16) | ((unsigned)(a3 & 255) << 24));
  }
  return out;
}

// pass 1: waves split q-rows (16 each); 8 tiles of 128 keys staged in LDS.
// T14 prefetch: next tile's K loaded into registers during compute.
// z summation tree unchanged -> bit-identical invz.
__global__ __launch_bounds__(256, 4) void k_pass1(
    const float* __restrict__ qf, int8_t* __restrict__ q8,
    const int8_t* __restrict__ k8,
    float* __restrict__ invz, unsigned* __restrict__ scal) {
  __shared__ __align__(16) int8_t kbuf[128 * 72];
  __shared__ float mared[4];
  int bh = blockIdx.y, b = bh >> 3, h = bh & 7;
  int wave = threadIdx.x >> 6, lane = threadIdx.x & 63;
  int l15 = lane & 15, g = lane >> 4;
  int row0 = blockIdx.x * 64;
  int myrow = row0 + wave * 16 + l15;
  const float aq = __uint_as_float(scal[0]), ak = __uint_as_float(scal[1]);
  const float alpha2 = (aq * ak) * (0.125f / (127.0f * 127.0f)) * 1.44269504f;
  const float sq = 127.0f / aq;
  const v4i z4 = {0, 0, 0, 0};
  size_t qoff = (size_t)(b * NQ + myrow) * DMODEL + h * DH + g * 16;
  v4i qfrag = quant_pack16(qf + qoff, sq);
  *(v4i*)(q8 + qoff) = qfrag;
  const int8_t* kbase = k8 + (size_t)b * MK * DMODEL + h * DH;
  const int rs = threadIdx.x >> 2, qs = (threadIdx.x & 3) * 16;
  const int8_t* kls = kbase + (size_t)rs * DMODEL + qs;

  v4i kp0 = *(const v4i*)(kls);
  v4i kp1 = *(const v4i*)(kls + (size_t)64 * DMODEL);

  float z[4] = {0.f, 0.f, 0.f, 0.f};
  int mi = -(1 << 30);
  for (int tile = 0; tile < 8; ++tile) {
    __syncthreads();
    *(v4i*)(&kbuf[rs * 72 + qs]) = kp0;
    *(v4i*)(&kbuf[(rs + 64) * 72 + qs]) = kp1;
    __syncthreads();
    if (tile < 7) {  // prefetch next tile; latency hides under compute below
      kp0 = *(const v4i*)(kls + (size_t)((tile + 1) * 128) * DMODEL);
      kp1 = *(const v4i*)(kls + (size_t)((tile + 1) * 128 + 64) * DMODEL);
    }
    float zt = z[tile >> 1];
#pragma unroll
    for (int t = 0; t < 8; ++t) {
      v4i kfrag = *(const v4i*)(&kbuf[(t * 16 + l15) * 72 + g * 16]);
      v4i sa = __builtin_amdgcn_mfma_i32_16x16x64_i8(kfrag, qfrag, z4, 0, 0, 0);
      mi = max(mi, max(max(sa[0], sa[1]), max(sa[2], sa[3])));
      float e0 = __builtin_amdgcn_exp2f((float)sa[0] * alpha2);
      float e1 = __builtin_amdgcn_exp2f((float)sa[1] * alpha2);
      float e2 = __builtin_amdgcn_exp2f((float)sa[2] * alpha2);
      float e3 = __builtin_amdgcn_exp2f((float)sa[3] * alpha2);
      zt += (e0 + e1) + (e2 + e3);
    }
    z[tile >> 1] = zt;
  }
#pragma unroll
  for (int i = 0; i < 4; ++i) {
    z[i] += __shfl_xor(z[i], 16, 64);
    z[i] += __shfl_xor(z[i], 32, 64);
  }
  mi = max(mi, __shfl_xor(mi, 16, 64));
  mi = max(mi, __shfl_xor(mi, 32, 64));
  float zt = (z[0] + z[1]) + (z[2] + z[3]);
  float iz = 1.0f / zt;
  if (g == 0) invz[(size_t)bh * NQ + myrow] = iz;
  float ma = __builtin_amdgcn_exp2f((float)mi * alpha2) * iz;  // row softmax max
#pragma unroll
  for (int off = 1; off < 16; off <<= 1)
    ma = fmaxf(ma, __shfl_xor(ma, off, 64));
  if (lane == 0) mared[wave] = ma;
  __syncthreads();
  if (threadIdx.x == 0)
    atomicMax(scal + 3,
              __float_as_uint(fmaxf(fmaxf(mared[0], mared[1]),
                                    fmaxf(mared[2], mared[3]))));
}

// pass 2: waves split q-rows; k/v tiles in block LDS with T14 register
// prefetch; wave-private attn round-trip; exact int32 PV accumulation.
// PV MFMA operands swapped (exact integer sums, order-free) so D holds 4
// consecutive dims per lane -> packed 8B v4bf stores instead of 16x2B.
__global__ __launch_bounds__(256, 4) void k_pass2(
    const int8_t* __restrict__ q8, const int8_t* __restrict__ k8,
    const int8_t* __restrict__ v8t, const float* __restrict__ invz,
    const unsigned* __restrict__ scal, __bf16* __restrict__ o) {
  __shared__ __align__(16) int8_t kbuf[128 * 72];
  __shared__ __align__(16) int8_t vbuf[64 * 152];
  __shared__ __align__(16) int8_t albuf[4][16 * 152];
  int bh = blockIdx.y, b = bh >> 3, h = bh & 7;
  int wave = threadIdx.x >> 6, lane = threadIdx.x & 63;
  int l15 = lane & 15, g = lane >> 4;
  int row0 = blockIdx.x * 64;
  int myrow = row0 + wave * 16 + l15;
  const float aq = __uint_as_float(scal[0]), ak = __uint_as_float(scal[1]);
  const float avv = __uint_as_float(scal[2]), izm = __uint_as_float(scal[3]);
  const float alpha2 = (aq * ak) * (0.125f / (127.0f * 127.0f)) * 1.44269504f;
  const float oscale = (izm / 127.0f) * (avv / 127.0f);
  const float MAGIC = 12582912.0f;  // 1.5 * 2^23
  const v4i z4 = {0, 0, 0, 0};

  v4i qfrag = *(const v4i*)(q8 + (size_t)(b * NQ + myrow) * DMODEL + h * DH + g * 16);
  const float lcr = __builtin_amdgcn_logf(invz[(size_t)bh * NQ + myrow] * (127.0f / izm));
  const int8_t* kbase = k8 + (size_t)b * MK * DMODEL + h * DH;
  const int8_t* vbase = v8t + (size_t)bh * DH * MK;
  int8_t* alds = albuf[wave];
  const int rs = threadIdx.x >> 2, qs = (threadIdx.x & 3) * 16;
  const int vr = threadIdx.x >> 3, vq = (threadIdx.x & 7) * 16;
  const int8_t* kls = kbase + (size_t)rs * DMODEL + qs;
  const int8_t* vls = vbase + (size_t)vr * MK + vq;

  v4i kp0 = *(const v4i*)(kls);
  v4i kp1 = *(const v4i*)(kls + (size_t)64 * DMODEL);
  v4i vp0 = *(const v4i*)(vls);
  v4i vp1 = *(const v4i*)(vls + (size_t)32 * MK);

  v4i pacc[4] = {};
  for (int tile = 0; tile < 8; ++tile) {
    __syncthreads();
    *(v4i*)(&kbuf[rs * 72 + qs]) = kp0;
    *(v4i*)(&kbuf[(rs + 64) * 72 + qs]) = kp1;
    *(v4i*)(&vbuf[vr * 152 + vq]) = vp0;
    *(v4i*)(&vbuf[(vr + 32) * 152 + vq]) = vp1;
    __syncthreads();
    if (tile < 7) {  // prefetch next tile; hides under QK^T + softmax + PV
      kp0 = *(const v4i*)(kls + (size_t)((tile + 1) * 128) * DMODEL);
      kp1 = *(const v4i*)(kls + (size_t)((tile + 1) * 128 + 64) * DMODEL);
      vp0 = *(const v4i*)(vls + (tile + 1) * 128);
      vp1 = *(const v4i*)(vls + (size_t)32 * MK + (tile + 1) * 128);
    }
#pragma unroll
    for (int t = 0; t < 8; ++t) {
      v4i kfrag = *(const v4i*)(&kbuf[(t * 16 + l15) * 72 + g * 16]);
      v4i sa = __builtin_amdgcn_mfma_i32_16x16x64_i8(kfrag, qfrag, z4, 0, 0, 0);
      float f0 = __builtin_amdgcn_exp2f(fmaf((float)sa[0], alpha2, lcr)) + MAGIC;
      float f1 = __builtin_amdgcn_exp2f(fmaf((float)sa[1], alpha2, lcr)) + MAGIC;
      float f2 = __builtin_amdgcn_exp2f(fmaf((float)sa[2], alpha2, lcr)) + MAGIC;
      float f3 = __builtin_amdgcn_exp2f(fmaf((float)sa[3], alpha2, lcr)) + MAGIC;
      unsigned packed = (__float_as_uint(f0) & 255u) |
                        ((__float_as_uint(f1) & 255u) << 8) |
                        ((__float_as_uint(f2) & 255u) << 16) |
                        (__float_as_uint(f3) << 24);
      *(unsigned*)(alds + l15 * 152 + t * 16 + g * 4) = packed;
    }
#pragma unroll
    for (int c = 0; c < 2; ++c) {
      v4i afrag = *(const v4i*)(alds + l15 * 152 + c * 64 + g * 16);
#pragma unroll
      for (int d = 0; d < 4; ++d) {
        v4i vfrag = *(const v4i*)(&vbuf[(d * 16 + l15) * 152 + c * 64 + g * 16]);
        // swapped operands: D[dim][qrow] -> lane l15 = qrow, rows = dims
        pacc[d] = __builtin_amdgcn_mfma_i32_16x16x64_i8(vfrag, afrag, pacc[d], 0, 0, 0);
      }
    }
  }
  // D: col(l15)=qrow, row(g*4+r)=dim-within-16 -> 4 consecutive dims per lane
  __bf16* obase = o + (size_t)(b * NQ + row0 + wave * 16 + l15) * DMODEL + h * DH;
#pragma unroll
  for (int d = 0; d < 4; ++d) {
    v4bf ov;
#pragma unroll
    for (int r = 0; r < 4; ++r)
      ov[r] = (__bf16)((float)pacc[d][r] * oscale);
    *(v4bf*)(obase + d * 16 + g * 4) = ov;
  }
}

extern "C" void kernel_launch(void* const* d_in, const int* in_sizes, int n_in,
                              void* d_out, int out_size, void* d_ws, size_t ws_size,
                              hipStream_t stream) {
  (void)in_sizes; (void)n_in; (void)out_size; (void)ws_size;
  const float* x   = (const float*)d_in[0];
  const float* ctx = (const float*)d_in[1];
  const float* Wq  = (const float*)d_in[2];
  const float* Wk  = (const float*)d_in[3];
  const float* Wv  = (const float*)d_in[4];
  const float* Wo  = (const float*)d_in[5];
  const float* bo  = (const float*)d_in[6];
  float* out = (float*)d_out;

  char* ws = (char*)d_ws;
  size_t off = 0;
  auto alloc = [&](size_t bytes) {
    char* p = ws + off;
    off += (bytes + 255) & ~(size_t)255;
    return p;
  };
  unsigned* scal = (unsigned*)alloc(16);
  __bf16* Wq_t = (__bf16*)alloc((size_t)512 * 512 * 2);
  __bf16* Wk_t = (__bf16*)alloc((size_t)512 * 768 * 2);  // contiguous with Wv_t
  __bf16* Wv_t = (__bf16*)alloc((size_t)512 * 768 * 2);
  __bf16* Wo_t = (__bf16*)alloc((size_t)512 * 512 * 2);
  __bf16* xb   = (__bf16*)alloc((size_t)BATCH * NQ * DMODEL * 2);
  __bf16* cb   = (__bf16*)alloc((size_t)BATCH * MK * DCTX * 2);
  float* qf  = (float*)alloc((size_t)BATCH * NQ * DMODEL * 4);   // later reused as o
  float* kvf = (float*)alloc((size_t)BATCH * MK * 1024 * 4);     // [2048][1024]: k | v
  int8_t* q8 = (int8_t*)alloc((size_t)BATCH * NQ * DMODEL);
  int8_t* k8 = (int8_t*)alloc((size_t)BATCH * MK * DMODEL);
  int8_t* v8t = (int8_t*)alloc((size_t)BATCH * NH * DH * MK);
  float* invz = (float*)alloc((size_t)BATCH * NH * NQ * 4);
  __bf16* o = (__bf16*)qf;  // q_f32 dead after pass1 quantizes it

  k_prep<<<4352, 256, 0, stream>>>(x, ctx, xb, cb, Wq, Wk, Wv, Wo,
                                   Wq_t, Wk_t, Wv_t, Wo_t, scal);
  k_gemm_qkv<<<1024, 256, 0, stream>>>(xb, Wq_t, qf, cb, Wk_t, kvf, scal);
  k_quant_kv<<<1280, 256, 0, stream>>>(kvf, k8, v8t, scal);
  k_pass1<<<dim3(64, 16), 256, 0, stream>>>(qf, q8, k8, invz, scal);
  k_pass2<<<dim3(64, 16), 256, 0, stream>>>(q8, k8, v8t, invz, scal, o);
  k_gemm_out<<<512, 256, 0, stream>>>(o, Wo_t, out, bo);
}

// Round 5
// 175.306 us; speedup vs baseline: 1.1053x; 1.0151x over previous
//
#include <hip/hip_runtime.h>
#include <stdint.h>

typedef float  v4f  __attribute__((ext_vector_type(4)));
typedef int    v4i  __attribute__((ext_vector_type(4)));
typedef __bf16 v8bf __attribute__((ext_vector_type(8)));
typedef __bf16 v4bf __attribute__((ext_vector_type(4)));

#define BATCH  2
#define NQ     4096
#define MK     1024
#define DMODEL 512
#define DCTX   768
#define NH     8
#define DH     64

// Merged prep: blocks [0,2816) convert x/ctx fp32->bf16 (RNE -> bits identical
// to inline-cvt GEMM path); blocks [2816,4352) transpose weights to
// Wt[512][K] bf16. Block 2816 zero-inits scal.
__global__ __launch_bounds__(256) void k_prep(
    const float* __restrict__ x, const float* __restrict__ ctx,
    __bf16* __restrict__ xb, __bf16* __restrict__ cb,
    const float* __restrict__ Wq, const float* __restrict__ Wk,
    const float* __restrict__ Wv, const float* __restrict__ Wo,
    __bf16* __restrict__ Wq_t, __bf16* __restrict__ Wk_t,
    __bf16* __restrict__ Wv_t, __bf16* __restrict__ Wo_t,
    unsigned* __restrict__ scal) {
  int bx = blockIdx.x;
  if (bx < 2816) {
    const int XC = BATCH * NQ * DMODEL / 8;
    const int CC = BATCH * MK * DCTX / 8;
    int idx = bx * 256 + threadIdx.x;
    const float* src; __bf16* dst;
    if (idx < XC) { src = x + (size_t)idx * 8; dst = xb + (size_t)idx * 8; }
    else {
      int j = idx - XC;
      if (j >= CC) return;
      src = ctx + (size_t)j * 8; dst = cb + (size_t)j * 8;
    }
    float4 a = *(const float4*)src, b = *(const float4*)(src + 4);
    v8bf o = { (__bf16)a.x, (__bf16)a.y, (__bf16)a.z, (__bf16)a.w,
               (__bf16)b.x, (__bf16)b.y, (__bf16)b.z, (__bf16)b.w };
    *(v8bf*)dst = o;
    return;
  }
  int id = bx - 2816;
  if (id == 0 && threadIdx.x < 4) scal[threadIdx.x] = 0u;
  int tx = id & 15, rem = id >> 4;
  int ty = rem % 24, tz = rem / 24;
  const float* src; __bf16* dst; int K;
  switch (tz) {
    case 0:  src = Wq; dst = Wq_t; K = DMODEL; break;
    case 1:  src = Wk; dst = Wk_t; K = DCTX;   break;
    case 2:  src = Wv; dst = Wv_t; K = DCTX;   break;
    default: src = Wo; dst = Wo_t; K = DMODEL; break;
  }
  int k0 = ty * 32;
  if (k0 >= K) return;
  int n0 = tx * 32;
  __shared__ __bf16 tile[32][33];
  int c = threadIdx.x & 31, r0 = threadIdx.x >> 5;
  for (int i = 0; i < 4; ++i) {
    int r = r0 + i * 8;
    tile[c][r] = (__bf16)src[(size_t)(k0 + r) * DMODEL + n0 + c];
  }
  __syncthreads();
  for (int i = 0; i < 4; ++i) {
    int r = r0 + i * 8;
    dst[(size_t)(n0 + r) * K + k0 + c] = tile[r][c];
  }
}

// B-stationary GEMM body v2 (r4/r5): C tile = A[256 rows][K_] @ Bt[NC cols][K_]^T.
// 64 rows/wave (AF=4 fragments) -> 16 MFMAs per JT=4 ds_reads (4:1 density).
// NC-col B panel for ALL K in LDS (one barrier); K-loop barrier-free;
// depth-2 A register prefetch + double-buffered B ds_reads, all statically
// indexed under full unroll (rule #20).
// Per-element k-ascending MFMA chain unchanged -> bit-identical C.
template<int K_, int NC, bool BIAS, bool AMAX>
__device__ __forceinline__ void gemm_body(
    char* smemraw, const __bf16* __restrict__ A, const __bf16* __restrict__ Bt,
    float* __restrict__ C, int N, int rowBlk, int colBlk,
    const float* __restrict__ bias,
    unsigned* __restrict__ amaxLo, unsigned* __restrict__ amaxHi) {
  constexpr int CS = K_ + 8;
  constexpr int GPC = K_ / 8;
  constexpr int JT = NC / 16;
  constexpr int NIT = K_ / 32;
  constexpr int AD = 2;  // A prefetch depth
  constexpr int AF = 4;  // row fragments per wave (64 rows)
  __bf16* Bs = (__bf16*)smemraw;
  float* redmax = (float*)(smemraw + (size_t)NC * CS * 2);
  const int tid = threadIdx.x;
  const int lane = tid & 63, wave = tid >> 6;
  const int l15 = lane & 15, g = lane >> 4;
  const int col0 = colBlk * NC;
  const int row0w = rowBlk * 256 + wave * 64;

#pragma unroll
  for (int i = 0; i < NC * GPC / 256; ++i) {
    int f = i * 256 + tid;
    int c = f / GPC, w = f - c * GPC;
    *(v8bf*)(&Bs[c * CS + w * 8]) =
        *(const v8bf*)(Bt + (size_t)(col0 + c) * K_ + w * 8);
  }

  const __bf16* ap[AF];
#pragma unroll
  for (int f = 0; f < AF; ++f)
    ap[f] = A + (size_t)(row0w + f * 16 + l15) * K_ + g * 8;

  // prologue A prefetch: independent of LDS, overlaps the staging barrier
  v8bf abuf[AF][AD];
#pragma unroll
  for (int i = 0; i < AD; ++i)
#pragma unroll
    for (int f = 0; f < AF; ++f)
      abuf[f][i] = *(const v8bf*)(ap[f] + i * 32);
  __syncthreads();

  v8bf bbuf[2][JT];
#pragma unroll
  for (int j = 0; j < JT; ++j)
    bbuf[0][j] = *(const v8bf*)(&Bs[(j * 16 + l15) * CS + g * 8]);

  v4f acc[AF][JT] = {};
#pragma unroll
  for (int it = 0; it < NIT; ++it) {
    const int cur = it & 1, nxt = cur ^ 1;
    if (it + 1 < NIT) {
#pragma unroll
      for (int j = 0; j < JT; ++j)
        bbuf[nxt][j] =
            *(const v8bf*)(&Bs[(j * 16 + l15) * CS + (it + 1) * 32 + g * 8]);
    }
    v8bf af[AF];
#pragma unroll
    for (int f = 0; f < AF; ++f) {
      af[f] = abuf[f][it % AD];
      if (it + AD < NIT)  // refill slot for iteration it+AD
        abuf[f][it % AD] = *(const v8bf*)(ap[f] + (it + AD) * 32);
    }
#pragma unroll
    for (int f = 0; f < AF; ++f)
#pragma unroll
      for (int j = 0; j < JT; ++j)
        acc[f][j] = __builtin_amdgcn_mfma_f32_16x16x32_bf16(
            af[f], bbuf[cur][j], acc[f][j], 0, 0, 0);
  }

  float lmax = 0.0f;
#pragma unroll
  for (int j = 0; j < JT; ++j) {
    int col = col0 + j * 16 + l15;
    float bv = BIAS ? bias[col] : 0.0f;
#pragma unroll
    for (int f = 0; f < AF; ++f) {
#pragma unroll
      for (int r = 0; r < 4; ++r) {
        int row = row0w + f * 16 + g * 4 + r;  // C/D: col=lane&15, row=quad*4+reg
        float cv = acc[f][j][r] + bv;
        C[(size_t)row * N + col] = cv;
        if (AMAX) lmax = fmaxf(lmax, fabsf(cv));
      }
    }
  }
  if (AMAX) {
    for (int off = 32; off > 0; off >>= 1)
      lmax = fmaxf(lmax, __shfl_xor(lmax, off, 64));
    if (lane == 0) redmax[wave] = lmax;
    __syncthreads();
    if (tid == 0) {
      float bm = fmaxf(fmaxf(redmax[0], redmax[1]), fmaxf(redmax[2], redmax[3]));
      atomicMax(col0 < 512 ? amaxLo : amaxHi, __float_as_uint(bm));
    }
  }
}

// Fused projections with XCD-aware work assignment (r2, proven on FETCH):
// all column-panels of one A row-panel land on the same XCD L2.
// blocks [0,256) = q GEMM (8192x512: 32 rowBlks x 8 colBlks, 4 rowBlks/XCD);
// [256,512) = kv GEMM (2048x1024: 8 rowBlks x 32 colBlks, 1 rowBlk/XCD).
__global__ __launch_bounds__(256, 2) void k_gemm_qkv(
    const __bf16* __restrict__ xb, const __bf16* __restrict__ Wq_t,
    float* __restrict__ qf,
    const __bf16* __restrict__ cb, const __bf16* __restrict__ Wkv_t,
    float* __restrict__ kvf, unsigned* __restrict__ scal) {
  __shared__ __align__(16) char smem[64 * (512 + 8) * 2 + 16];
  int bid = blockIdx.x;
  if (bid < 256) {
    int xcd = bid & 7, w = bid >> 3;   // w in [0,32)
    gemm_body<512, 64, false, true>(smem, xb, Wq_t, qf, 512,
                                    xcd * 4 + (w >> 3), w & 7, nullptr,
                                    scal + 0, scal + 0);
  } else {
    int id = bid - 256;                // 256%8==0 -> id%8 == bid%8
    int xcd = id & 7, w = id >> 3;     // w in [0,32)
    gemm_body<768, 32, false, true>(smem, cb, Wkv_t, kvf, 1024,
                                    xcd, w, nullptr,
                                    scal + 1, scal + 2);
  }
}

// 256 blocks: 32 rowBlks x 8 colBlks (4 rowBlks/XCD). Grid MUST be 256 with
// the 256-row tile (r4 crash: stale 512-block launch wrote rows past 8192).
__global__ __launch_bounds__(256, 2) void k_gemm_out(
    const __bf16* __restrict__ o, const __bf16* __restrict__ Wo_t,
    float* __restrict__ out, const float* __restrict__ bo) {
  __shared__ __align__(16) char smem[64 * (512 + 8) * 2 + 16];
  int xcd = blockIdx.x & 7, w = blockIdx.x >> 3;
  gemm_body<512, 64, true, false>(smem, o, Wo_t, out, 512,
                                  xcd * 4 + (w >> 3), w & 7, bo,
                                  nullptr, nullptr);
}

// k/v quantization: blocks [0,1024) quantize k; [1024,1280) transpose-quantize v.
__global__ __launch_bounds__(256) void k_quant_kv(
    const float* __restrict__ kvf,
    int8_t* __restrict__ k8, int8_t* __restrict__ v8t,
    const unsigned* __restrict__ scal) {
  __shared__ int8_t tile[64][80];
  int bx = blockIdx.x;
  if (bx < 1024) {
    int j = bx * 256 + threadIdx.x;
    int r = j >> 7;
    int c4 = (j & 127) << 2;
    float4 v = *(const float4*)(kvf + (size_t)r * 1024 + c4);
    float s = 127.0f / __uint_as_float(scal[1]);
    int a0 = __float2int_rn(v.x * s), a1 = __float2int_rn(v.y * s);
    int a2 = __float2int_rn(v.z * s), a3 = __float2int_rn(v.w * s);
    a0 = max(-128, min(127, a0)); a1 = max(-128, min(127, a1));
    a2 = max(-128, min(127, a2)); a3 = max(-128, min(127, a3));
    unsigned p = (unsigned)(a0 & 255) | ((unsigned)(a1 & 255) << 8) |
                 ((unsigned)(a2 & 255) << 16) | ((unsigned)(a3 & 255) << 24);
    *(unsigned*)(k8 + (size_t)j * 4) = p;
    return;
  }
  int id = bx - 1024;
  int bh = id >> 4, b = bh >> 3, h = bh & 7;
  int j0 = (id & 15) * 64;
  const float s = 127.0f / __uint_as_float(scal[2]);
  int t = threadIdx.x;
  int j = t >> 2, dh0 = (t & 3) << 4;
  const float* src = kvf + (size_t)(b * MK + j0 + j) * 1024 + 512 + h * DH + dh0;
#pragma unroll
  for (int i = 0; i < 16; i += 4) {
    float4 v = *(const float4*)(src + i);
    int a0 = __float2int_rn(v.x * s), a1 = __float2int_rn(v.y * s);
    int a2 = __float2int_rn(v.z * s), a3 = __float2int_rn(v.w * s);
    tile[dh0 + i + 0][j] = (int8_t)max(-128, min(127, a0));
    tile[dh0 + i + 1][j] = (int8_t)max(-128, min(127, a1));
    tile[dh0 + i + 2][j] = (int8_t)max(-128, min(127, a2));
    tile[dh0 + i + 3][j] = (int8_t)max(-128, min(127, a3));
  }
  __syncthreads();
  int dh = t >> 2, jb = (t & 3) << 4;
  v4i val = *(const v4i*)(&tile[dh][jb]);
  *(v4i*)(v8t + (size_t)(bh * DH + dh) * MK + j0 + jb) = val;
}

__device__ __forceinline__ v4i quant_pack16(const float* p, float s) {
  v4i out;
#pragma unroll
  for (int q = 0; q < 4; ++q) {
    float4 v = *(const float4*)(p + q * 4);
    int a0 = __float2int_rn(v.x * s), a1 = __float2int_rn(v.y * s);
    int a2 = __float2int_rn(v.z * s), a3 = __float2int_rn(v.w * s);
    a0 = max(-128, min(127, a0)); a1 = max(-128, min(127, a1));
    a2 = max(-128, min(127, a2)); a3 = max(-128, min(127, a3));
    out[q] = (int)((unsigned)(a0 & 255) | ((unsigned)(a1 & 255) << 8) |
                   ((unsigned)(a2 & 255) << 16) | ((unsigned)(a3 & 255) << 24));
  }
  return out;
}

// pass 1: waves split q-rows (16 each); 8 tiles of 128 keys staged in LDS.
// T14 prefetch: next tile's K loaded into registers during compute.
// z summation tree unchanged -> bit-identical invz.
__global__ __launch_bounds__(256, 4) void k_pass1(
    const float* __restrict__ qf, int8_t* __restrict__ q8,
    const int8_t* __restrict__ k8,
    float* __restrict__ invz, unsigned* __restrict__ scal) {
  __shared__ __align__(16) int8_t kbuf[128 * 72];
  __shared__ float mared[4];
  int bh = blockIdx.y, b = bh >> 3, h = bh & 7;
  int wave = threadIdx.x >> 6, lane = threadIdx.x & 63;
  int l15 = lane & 15, g = lane >> 4;
  int row0 = blockIdx.x * 64;
  int myrow = row0 + wave * 16 + l15;
  const float aq = __uint_as_float(scal[0]), ak = __uint_as_float(scal[1]);
  const float alpha2 = (aq * ak) * (0.125f / (127.0f * 127.0f)) * 1.44269504f;
  const float sq = 127.0f / aq;
  const v4i z4 = {0, 0, 0, 0};
  size_t qoff = (size_t)(b * NQ + myrow) * DMODEL + h * DH + g * 16;
  v4i qfrag = quant_pack16(qf + qoff, sq);
  *(v4i*)(q8 + qoff) = qfrag;
  const int8_t* kbase = k8 + (size_t)b * MK * DMODEL + h * DH;
  const int rs = threadIdx.x >> 2, qs = (threadIdx.x & 3) * 16;
  const int8_t* kls = kbase + (size_t)rs * DMODEL + qs;

  v4i kp0 = *(const v4i*)(kls);
  v4i kp1 = *(const v4i*)(kls + (size_t)64 * DMODEL);

  float z[4] = {0.f, 0.f, 0.f, 0.f};
  int mi = -(1 << 30);
  for (int tile = 0; tile < 8; ++tile) {
    __syncthreads();
    *(v4i*)(&kbuf[rs * 72 + qs]) = kp0;
    *(v4i*)(&kbuf[(rs + 64) * 72 + qs]) = kp1;
    __syncthreads();
    if (tile < 7) {  // prefetch next tile; latency hides under compute below
      kp0 = *(const v4i*)(kls + (size_t)((tile + 1) * 128) * DMODEL);
      kp1 = *(const v4i*)(kls + (size_t)((tile + 1) * 128 + 64) * DMODEL);
    }
    float zt = z[tile >> 1];
#pragma unroll
    for (int t = 0; t < 8; ++t) {
      v4i kfrag = *(const v4i*)(&kbuf[(t * 16 + l15) * 72 + g * 16]);
      v4i sa = __builtin_amdgcn_mfma_i32_16x16x64_i8(kfrag, qfrag, z4, 0, 0, 0);
      mi = max(mi, max(max(sa[0], sa[1]), max(sa[2], sa[3])));
      float e0 = __builtin_amdgcn_exp2f((float)sa[0] * alpha2);
      float e1 = __builtin_amdgcn_exp2f((float)sa[1] * alpha2);
      float e2 = __builtin_amdgcn_exp2f((float)sa[2] * alpha2);
      float e3 = __builtin_amdgcn_exp2f((float)sa[3] * alpha2);
      zt += (e0 + e1) + (e2 + e3);
    }
    z[tile >> 1] = zt;
  }
#pragma unroll
  for (int i = 0; i < 4; ++i) {
    z[i] += __shfl_xor(z[i], 16, 64);
    z[i] += __shfl_xor(z[i], 32, 64);
  }
  mi = max(mi, __shfl_xor(mi, 16, 64));
  mi = max(mi, __shfl_xor(mi, 32, 64));
  float zt = (z[0] + z[1]) + (z[2] + z[3]);
  float iz = 1.0f / zt;
  if (g == 0) invz[(size_t)bh * NQ + myrow] = iz;
  float ma = __builtin_amdgcn_exp2f((float)mi * alpha2) * iz;  // row softmax max
#pragma unroll
  for (int off = 1; off < 16; off <<= 1)
    ma = fmaxf(ma, __shfl_xor(ma, off, 64));
  if (lane == 0) mared[wave] = ma;
  __syncthreads();
  if (threadIdx.x == 0)
    atomicMax(scal + 3,
              __float_as_uint(fmaxf(fmaxf(mared[0], mared[1]),
                                    fmaxf(mared[2], mared[3]))));
}

// pass 2: waves split q-rows; k/v tiles in block LDS with T14 register
// prefetch; wave-private attn round-trip; exact int32 PV accumulation.
// PV MFMA operands swapped (exact integer sums, order-free) so D holds 4
// consecutive dims per lane -> packed 8B v4bf stores instead of 16x2B.
__global__ __launch_bounds__(256, 4) void k_pass2(
    const int8_t* __restrict__ q8, const int8_t* __restrict__ k8,
    const int8_t* __restrict__ v8t, const float* __restrict__ invz,
    const unsigned* __restrict__ scal, __bf16* __restrict__ o) {
  __shared__ __align__(16) int8_t kbuf[128 * 72];
  __shared__ __align__(16) int8_t vbuf[64 * 152];
  __shared__ __align__(16) int8_t albuf[4][16 * 152];
  int bh = blockIdx.y, b = bh >> 3, h = bh & 7;
  int wave = threadIdx.x >> 6, lane = threadIdx.x & 63;
  int l15 = lane & 15, g = lane >> 4;
  int row0 = blockIdx.x * 64;
  int myrow = row0 + wave * 16 + l15;
  const float aq = __uint_as_float(scal[0]), ak = __uint_as_float(scal[1]);
  const float avv = __uint_as_float(scal[2]), izm = __uint_as_float(scal[3]);
  const float alpha2 = (aq * ak) * (0.125f / (127.0f * 127.0f)) * 1.44269504f;
  const float oscale = (izm / 127.0f) * (avv / 127.0f);
  const float MAGIC = 12582912.0f;  // 1.5 * 2^23
  const v4i z4 = {0, 0, 0, 0};

  v4i qfrag = *(const v4i*)(q8 + (size_t)(b * NQ + myrow) * DMODEL + h * DH + g * 16);
  const float lcr = __builtin_amdgcn_logf(invz[(size_t)bh * NQ + myrow] * (127.0f / izm));
  const int8_t* kbase = k8 + (size_t)b * MK * DMODEL + h * DH;
  const int8_t* vbase = v8t + (size_t)bh * DH * MK;
  int8_t* alds = albuf[wave];
  const int rs = threadIdx.x >> 2, qs = (threadIdx.x & 3) * 16;
  const int vr = threadIdx.x >> 3, vq = (threadIdx.x & 7) * 16;
  const int8_t* kls = kbase + (size_t)rs * DMODEL + qs;
  const int8_t* vls = vbase + (size_t)vr * MK + vq;

  v4i kp0 = *(const v4i*)(kls);
  v4i kp1 = *(const v4i*)(kls + (size_t)64 * DMODEL);
  v4i vp0 = *(const v4i*)(vls);
  v4i vp1 = *(const v4i*)(vls + (size_t)32 * MK);

  v4i pacc[4] = {};
  for (int tile = 0; tile < 8; ++tile) {
    __syncthreads();
    *(v4i*)(&kbuf[rs * 72 + qs]) = kp0;
    *(v4i*)(&kbuf[(rs + 64) * 72 + qs]) = kp1;
    *(v4i*)(&vbuf[vr * 152 + vq]) = vp0;
    *(v4i*)(&vbuf[(vr + 32) * 152 + vq]) = vp1;
    __syncthreads();
    if (tile < 7) {  // prefetch next tile; hides under QK^T + softmax + PV
      kp0 = *(const v4i*)(kls + (size_t)((tile + 1) * 128) * DMODEL);
      kp1 = *(const v4i*)(kls + (size_t)((tile + 1) * 128 + 64) * DMODEL);
      vp0 = *(const v4i*)(vls + (tile + 1) * 128);
      vp1 = *(const v4i*)(vls + (size_t)32 * MK + (tile + 1) * 128);
    }
#pragma unroll
    for (int t = 0; t < 8; ++t) {
      v4i kfrag = *(const v4i*)(&kbuf[(t * 16 + l15) * 72 + g * 16]);
      v4i sa = __builtin_amdgcn_mfma_i32_16x16x64_i8(kfrag, qfrag, z4, 0, 0, 0);
      float f0 = __builtin_amdgcn_exp2f(fmaf((float)sa[0], alpha2, lcr)) + MAGIC;
      float f1 = __builtin_amdgcn_exp2f(fmaf((float)sa[1], alpha2, lcr)) + MAGIC;
      float f2 = __builtin_amdgcn_exp2f(fmaf((float)sa[2], alpha2, lcr)) + MAGIC;
      float f3 = __builtin_amdgcn_exp2f(fmaf((float)sa[3], alpha2, lcr)) + MAGIC;
      unsigned packed = (__float_as_uint(f0) & 255u) |
                        ((__float_as_uint(f1) & 255u) << 8) |
                        ((__float_as_uint(f2) & 255u) << 16) |
                        (__float_as_uint(f3) << 24);
      *(unsigned*)(alds + l15 * 152 + t * 16 + g * 4) = packed;
    }
#pragma unroll
    for (int c = 0; c < 2; ++c) {
      v4i afrag = *(const v4i*)(alds + l15 * 152 + c * 64 + g * 16);
#pragma unroll
      for (int d = 0; d < 4; ++d) {
        v4i vfrag = *(const v4i*)(&vbuf[(d * 16 + l15) * 152 + c * 64 + g * 16]);
        // swapped operands: D[dim][qrow] -> lane l15 = qrow, rows = dims
        pacc[d] = __builtin_amdgcn_mfma_i32_16x16x64_i8(vfrag, afrag, pacc[d], 0, 0, 0);
      }
    }
  }
  // D: col(l15)=qrow, row(g*4+r)=dim-within-16 -> 4 consecutive dims per lane
  __bf16* obase = o + (size_t)(b * NQ + row0 + wave * 16 + l15) * DMODEL + h * DH;
#pragma unroll
  for (int d = 0; d < 4; ++d) {
    v4bf ov;
#pragma unroll
    for (int r = 0; r < 4; ++r)
      ov[r] = (__bf16)((float)pacc[d][r] * oscale);
    *(v4bf*)(obase + d * 16 + g * 4) = ov;
  }
}

extern "C" void kernel_launch(void* const* d_in, const int* in_sizes, int n_in,
                              void* d_out, int out_size, void* d_ws, size_t ws_size,
                              hipStream_t stream) {
  (void)in_sizes; (void)n_in; (void)out_size; (void)ws_size;
  const float* x   = (const float*)d_in[0];
  const float* ctx = (const float*)d_in[1];
  const float* Wq  = (const float*)d_in[2];
  const float* Wk  = (const float*)d_in[3];
  const float* Wv  = (const float*)d_in[4];
  const float* Wo  = (const float*)d_in[5];
  const float* bo  = (const float*)d_in[6];
  float* out = (float*)d_out;

  char* ws = (char*)d_ws;
  size_t off = 0;
  auto alloc = [&](size_t bytes) {
    char* p = ws + off;
    off += (bytes + 255) & ~(size_t)255;
    return p;
  };
  unsigned* scal = (unsigned*)alloc(16);
  __bf16* Wq_t = (__bf16*)alloc((size_t)512 * 512 * 2);
  __bf16* Wk_t = (__bf16*)alloc((size_t)512 * 768 * 2);  // contiguous with Wv_t
  __bf16* Wv_t = (__bf16*)alloc((size_t)512 * 768 * 2);
  __bf16* Wo_t = (__bf16*)alloc((size_t)512 * 512 * 2);
  __bf16* xb   = (__bf16*)alloc((size_t)BATCH * NQ * DMODEL * 2);
  __bf16* cb   = (__bf16*)alloc((size_t)BATCH * MK * DCTX * 2);
  float* qf  = (float*)alloc((size_t)BATCH * NQ * DMODEL * 4);   // later reused as o
  float* kvf = (float*)alloc((size_t)BATCH * MK * 1024 * 4);     // [2048][1024]: k | v
  int8_t* q8 = (int8_t*)alloc((size_t)BATCH * NQ * DMODEL);
  int8_t* k8 = (int8_t*)alloc((size_t)BATCH * MK * DMODEL);
  int8_t* v8t = (int8_t*)alloc((size_t)BATCH * NH * DH * MK);
  float* invz = (float*)alloc((size_t)BATCH * NH * NQ * 4);
  __bf16* o = (__bf16*)qf;  // q_f32 dead after pass1 quantizes it

  k_prep<<<4352, 256, 0, stream>>>(x, ctx, xb, cb, Wq, Wk, Wv, Wo,
                                   Wq_t, Wk_t, Wv_t, Wo_t, scal);
  k_gemm_qkv<<<512, 256, 0, stream>>>(xb, Wq_t, qf, cb, Wk_t, kvf, scal);
  k_quant_kv<<<1280, 256, 0, stream>>>(kvf, k8, v8t, scal);
  k_pass1<<<dim3(64, 16), 256, 0, stream>>>(qf, q8, k8, invz, scal);
  k_pass2<<<dim3(64, 16), 256, 0, stream>>>(q8, k8, v8t, invz, scal, o);
  k_gemm_out<<<256, 256, 0, stream>>>(o, Wo_t, out, bo);
}